// Round 12
// baseline (129.906 us; speedup 1.0000x reference)
//
#include <hip/hip_runtime.h>
#include <hip/hip_bf16.h>

#define B_ 128
#define L_ 128
#define J_ 64
#define E_ 128
#define H_ 2
#define HD 64
#define S_ 129          // L+1
#define M_ (B_ * S_)    // 16512 tokens
#define CAT_ 1000
#define LN_EPS 1e-5f

typedef __attribute__((ext_vector_type(8))) short bf16x8;
typedef __attribute__((ext_vector_type(4))) float f32x4;
typedef __hip_bfloat16 bf16;

__device__ inline float bf2f(unsigned short u) {
    union { unsigned int i; float f; } v; v.i = (unsigned int)u << 16; return v.f;
}
__device__ inline unsigned short f2bu(float f) {
    __hip_bfloat16 h = __float2bfloat16(f);
    return *reinterpret_cast<unsigned short*>(&h);
}

// ---------------------------------------------------------------------------
// prep: transpose+convert weights to bf16 Bt[N][K]; pad lin1/lin2; pad bias;
// z=8/9: tables->bf16 WITH trailing zero row (catb[1000]=0, amtb[100]=0);
// z=10: zero hb; z=11: out = lin2 bias (every call).
// Wd bf16 offsets: q=0 k=16384 v=32768 o=49152 w1=65536 w2=81920
//                  lin1=98304 ([1024][128]) lin2=229376 ([1024][1024])
// ---------------------------------------------------------------------------
__global__ __launch_bounds__(256)
void prep_kernel(const float* __restrict__ Wq, const float* __restrict__ Wk,
                 const float* __restrict__ Wv, const float* __restrict__ Wo,
                 const float* __restrict__ W1, const float* __restrict__ W2,
                 const float* __restrict__ lin1W, const float* __restrict__ lin2W,
                 const float* __restrict__ lin1b, const float* __restrict__ lin2b,
                 const float* __restrict__ cat_table, const float* __restrict__ amount_table,
                 bf16* __restrict__ Wd, float* __restrict__ bias1024,
                 bf16* __restrict__ catb, bf16* __restrict__ amtb,
                 float* __restrict__ hb, float* __restrict__ outp) {
    const int z = blockIdx.z;
    const int tid = threadIdx.x;
    if (z == 8) {   // cat_table -> bf16, 1001 rows (row 1000 = zeros)
        const int gid = (blockIdx.x * 16 + blockIdx.y) * 256 + tid;
        for (int i = gid; i < 1001 * 128; i += 65536)
            catb[i] = (i < 1000 * 128) ? __float2bfloat16(cat_table[i])
                                       : __float2bfloat16(0.f);
        return;
    }
    if (z == 9) {   // amount_table -> bf16, 101 rows (row 100 = zeros)
        const int gid = (blockIdx.x * 16 + blockIdx.y) * 256 + tid;
        for (int i = gid; i < 101 * 128; i += 65536)
            amtb[i] = (i < 100 * 128) ? __float2bfloat16(amount_table[i])
                                      : __float2bfloat16(0.f);
        return;
    }
    if (z == 10) {  // zero hb [128][128] f32 (tail atomics accumulate into it)
        const int gid = (blockIdx.x * 16 + blockIdx.y) * 256 + tid;
        if (gid < B_ * E_) hb[gid] = 0.f;
        return;
    }
    if (z == 11) {  // out[128][1000] = lin2 bias (lin2 atomically adds partials)
        const int gid = (blockIdx.x * 16 + blockIdx.y) * 256 + tid;
        for (int i = gid; i < B_ * CAT_; i += 65536)
            outp[i] = lin2b[i % CAT_];
        return;
    }
    const float* src; bf16* dst; int Kd, Nd, sK, sN;
    switch (z) {
        case 0: src = Wq;    dst = Wd;          Kd = 128;  Nd = 128;  sK = 128;  sN = 128;  break;
        case 1: src = Wk;    dst = Wd + 16384;  Kd = 128;  Nd = 128;  sK = 128;  sN = 128;  break;
        case 2: src = Wv;    dst = Wd + 32768;  Kd = 128;  Nd = 128;  sK = 128;  sN = 128;  break;
        case 3: src = Wo;    dst = Wd + 49152;  Kd = 128;  Nd = 128;  sK = 128;  sN = 128;  break;
        case 4: src = W1;    dst = Wd + 65536;  Kd = 128;  Nd = 128;  sK = 128;  sN = 128;  break;
        case 5: src = W2;    dst = Wd + 81920;  Kd = 128;  Nd = 128;  sK = 128;  sN = 128;  break;
        case 6: src = lin1W; dst = Wd + 98304;  Kd = 128;  Nd = 1024; sK = 128;  sN = 1000; break;
        default:src = lin2W; dst = Wd + 229376; Kd = 1024; Nd = 1024; sK = 1000; sN = 1000; break;
    }
    if (z == 7 && blockIdx.x == 0 && blockIdx.y == 0) {
        for (int i = tid; i < 1024; i += 256)
            bias1024[i] = (i < 1000) ? lin1b[i] : 0.f;
    }
    const int k0 = blockIdx.x * 64, n0 = blockIdx.y * 64;
    if (k0 >= Kd || n0 >= Nd) return;
    __shared__ float t[64][65];
    const int c = tid & 63, r0 = tid >> 6;
    #pragma unroll 4
    for (int i = 0; i < 16; ++i) {
        const int r = r0 + i * 4;
        const int gk = k0 + r, gn = n0 + c;
        t[r][c] = (gk < sK && gn < sN) ? src[(size_t)gk * sN + gn] : 0.f;
    }
    __syncthreads();
    #pragma unroll 4
    for (int i = 0; i < 16; ++i) {
        const int r = r0 + i * 4;
        dst[(size_t)(n0 + r) * Kd + (k0 + c)] = __float2bfloat16(t[c][r]);
    }
}

// ---------------------------------------------------------------------------
// Embedding v4: 1 token/block, 256 threads = 8 j-groups x 32 lanes x 4 elems.
// 8-deep gather chains; pad mask folded into index at staging (zero rows);
// premultiplied byte offsets in LDS; 8-partial LDS reduce.
// ---------------------------------------------------------------------------
__global__ __launch_bounds__(256)
void embed_kernel(const int* __restrict__ cat_arr, const int* __restrict__ dt_arr,
                  const int* __restrict__ amount_arr, const int* __restrict__ id_arr,
                  const float* __restrict__ id_table, const bf16* __restrict__ catb,
                  const bf16* __restrict__ amtb, const float* __restrict__ dt_table,
                  float* __restrict__ x) {
    __shared__ int coff[64];
    __shared__ int aoff[64];
    __shared__ f32x4 red[8][32];
    const int tid = threadIdx.x;
    const int jg = tid >> 5, lg = tid & 31;
    const int t = blockIdx.x;
    const int b = t / S_, s = t - b * S_;

    if (s == 0) {      // id token: block-uniform early exit (before any barrier)
        if (tid < 32)
            *(float4*)(x + (size_t)t * E_ + tid * 4) =
                *(const float4*)(id_table + (size_t)id_arr[b] * E_ + tid * 4);
        return;
    }

    if (tid < 64) {
        const int base = (b * L_ + (s - 1)) * J_;
        const int c = cat_arr[base + tid];
        const int a = amount_arr[base + tid];
        const bool valid = (c != CAT_);
        coff[tid] = (valid ? c : CAT_) * E_;   // catb row 1000 is zeros
        aoff[tid] = (valid ? a : 100) * E_;    // amtb row 100 is zeros
    }
    __syncthreads();

    const int lg4 = lg * 4;
    f32x4 acc = {0.f, 0.f, 0.f, 0.f};
    #pragma unroll
    for (int jj = 0; jj < 8; ++jj) {
        const int j = jg * 8 + jj;
        const ushort4 cu = *(const ushort4*)(catb + coff[j] + lg4);
        const ushort4 au = *(const ushort4*)(amtb + aoff[j] + lg4);
        acc[0] += bf2f(cu.x) + bf2f(au.x);
        acc[1] += bf2f(cu.y) + bf2f(au.y);
        acc[2] += bf2f(cu.z) + bf2f(au.z);
        acc[3] += bf2f(cu.w) + bf2f(au.w);
    }
    if (jg) red[jg][lg] = acc;
    __syncthreads();

    if (jg == 0) {
        #pragma unroll
        for (int q = 1; q < 8; ++q) {
            const f32x4 r = red[q][lg];
            acc[0] += r[0]; acc[1] += r[1]; acc[2] += r[2]; acc[3] += r[3];
        }
        const float4 dv = *(const float4*)(
            dt_table + (size_t)dt_arr[b * L_ + s - 1] * E_ + lg4);
        float4 o;
        o.x = acc[0] + dv.x; o.y = acc[1] + dv.y;
        o.z = acc[2] + dv.z; o.w = acc[3] + dv.w;
        *(float4*)(x + (size_t)t * E_ + lg4) = o;
    }
}

// ---------------------------------------------------------------------------
// bf16 MFMA GEMM (QKV / lin1 / lin2 paths). ATOM: atomicAdd partials into Cf.
// ---------------------------------------------------------------------------
template<bool RELU, bool LN, bool HASRES, bool OF32, bool OBF16, bool SPLITK,
         bool AF32, bool QKV, bool ATOM>
__global__ __launch_bounds__(256)
void gemm_mfma(const void* __restrict__ Av, const bf16* __restrict__ Bt,
               const float* __restrict__ bias, const float* __restrict__ bias2,
               const float* __restrict__ bias3, const float* __restrict__ resid,
               float* __restrict__ Cf, bf16* __restrict__ Cb,
               bf16* __restrict__ Cb2, bf16* __restrict__ Cb3,
               const float* __restrict__ lng, const float* __restrict__ lnb,
               int K, int Nstride, int Nstore) {
    __shared__ bf16x8 Al[64 * 16];    // 16 KiB
    __shared__ bf16x8 Bl[128 * 16];   // 32 KiB
    const int tid = threadIdx.x;
    const int m0 = blockIdx.x * 64;
    const int n0 = QKV ? 0 : blockIdx.y * 128;
    const int w = tid >> 6, l = tid & 63;
    const int l15 = l & 15, g = l >> 4;
    f32x4 acc[8] = {};

    const bf16* BtX = Bt;
    const float* biasX = bias;
    bf16* CbX = Cb;
    if (QKV) {
        const int sel = blockIdx.y;
        BtX = Bt + sel * 16384;
        biasX = (sel == 0) ? bias : ((sel == 1) ? bias2 : bias3);
        CbX = (sel == 0) ? Cb : ((sel == 1) ? Cb2 : Cb3);
    }

    const int z = SPLITK ? blockIdx.z : 0;
    const int ksz = SPLITK ? (K / (int)gridDim.z) : K;
    const int kbeg = z * ksz;

    for (int kc = kbeg; kc < kbeg + ksz; kc += 128) {
        #pragma unroll
        for (int i = 0; i < 4; ++i) {
            const int lin = i * 256 + tid;
            const int r = lin >> 4, u = lin & 15;
            bf16x8 av;
            if (AF32) {
                const float* Af = (const float*)Av;
                const float4 f0 = *(const float4*)(Af + (size_t)(m0 + r) * K + kc + u * 8);
                const float4 f1 = *(const float4*)(Af + (size_t)(m0 + r) * K + kc + u * 8 + 4);
                av[0] = (short)f2bu(f0.x); av[1] = (short)f2bu(f0.y);
                av[2] = (short)f2bu(f0.z); av[3] = (short)f2bu(f0.w);
                av[4] = (short)f2bu(f1.x); av[5] = (short)f2bu(f1.y);
                av[6] = (short)f2bu(f1.z); av[7] = (short)f2bu(f1.w);
            } else {
                const bf16* Ab = (const bf16*)Av;
                av = *(const bf16x8*)(Ab + (size_t)(m0 + r) * K + kc + u * 8);
            }
            Al[r * 16 + (u ^ (r & 7))] = av;
        }
        #pragma unroll
        for (int i = 0; i < 8; ++i) {
            const int lin = i * 256 + tid;
            const int r = lin >> 4, u = lin & 15;
            Bl[r * 16 + (u ^ (r & 7))] =
                *(const bf16x8*)(BtX + (size_t)(n0 + r) * K + kc + u * 8);
        }
        __syncthreads();
        const int mr = w * 16 + l15;
        #pragma unroll
        for (int s = 0; s < 4; ++s) {
            const int ua = s * 4 + g;
            const bf16x8 a = Al[mr * 16 + (ua ^ (mr & 7))];
            #pragma unroll
            for (int nf = 0; nf < 8; ++nf) {
                const int nr = nf * 16 + l15;
                const bf16x8 b = Bl[nr * 16 + (ua ^ (nr & 7))];
                acc[nf] = __builtin_amdgcn_mfma_f32_16x16x32_bf16(a, b, acc[nf], 0, 0, 0);
            }
        }
        __syncthreads();
    }

    #pragma unroll
    for (int fr = 0; fr < 4; ++fr) {
        const int grow = m0 + w * 16 + g * 4 + fr;
        float v[8];
        float s1 = 0.f, s2 = 0.f;
        #pragma unroll
        for (int nf = 0; nf < 8; ++nf) {
            const int col = n0 + nf * 16 + l15;
            float xv = acc[nf][fr];
            if (!SPLITK && col < Nstore) xv += biasX[col];
            if (HASRES) xv += resid[(size_t)grow * Nstride + col];
            if (RELU) xv = fmaxf(xv, 0.f);
            v[nf] = xv;
            if (LN) { s1 += xv; s2 += xv * xv; }
        }
        if (LN) {
            #pragma unroll
            for (int off = 1; off < 16; off <<= 1) {
                s1 += __shfl_xor(s1, off);
                s2 += __shfl_xor(s2, off);
            }
            const float mu = s1 * (1.f / 128.f);
            const float rstd = rsqrtf(s2 * (1.f / 128.f) - mu * mu + LN_EPS);
            #pragma unroll
            for (int nf = 0; nf < 8; ++nf) {
                const int col = n0 + nf * 16 + l15;
                v[nf] = (v[nf] - mu) * rstd * lng[col] + lnb[col];
            }
        }
        float* Cfp = (SPLITK && !ATOM) ? (Cf + (size_t)z * (gridDim.x * 64) * Nstride) : Cf;
        #pragma unroll
        for (int nf = 0; nf < 8; ++nf) {
            const int col = n0 + nf * 16 + l15;
            if (col < Nstore) {
                if (OF32) {
                    if (ATOM) atomicAdd(&Cfp[(size_t)grow * Nstride + col], v[nf]);
                    else      Cfp[(size_t)grow * Nstride + col] = v[nf];
                }
                if (OBF16) CbX[(size_t)grow * Nstride + col] = __float2bfloat16(v[nf]);
            }
        }
    }
}

// ---------------------------------------------------------------------------
// Fused encoder tail + mean-pool (contention-free reduction).
//   X1 = LN1(X + O@Wo + bo); F1 = relu(X1@W1+b1); X = LN2(X1 + F1@W2 + b2);
//   pool: per-thread register partials -> shfl over g -> 4KB LDS over waves
//   -> 256 uncontended global atomicAdds into hb.
// ---------------------------------------------------------------------------
__global__ __launch_bounds__(256)
void encoder_tail(const bf16* __restrict__ Ob, const bf16* __restrict__ Wd,
                  const float* __restrict__ bo, const float* __restrict__ b1,
                  const float* __restrict__ b2,
                  const float* __restrict__ ln1g, const float* __restrict__ ln1b,
                  const float* __restrict__ ln2g, const float* __restrict__ ln2b,
                  float* __restrict__ X, float* __restrict__ hb) {
    __shared__ bf16x8 Al[64 * 16];    // 16 KiB
    __shared__ bf16x8 Bl[128 * 16];   // 32 KiB
    __shared__ float hbw[4][2][128];  // 4 KiB pool partials
    const int tid = threadIdx.x;
    const int m0 = blockIdx.x * 64;
    const int b0 = m0 / S_;
    const int w = tid >> 6, l = tid & 63;
    const int l15 = l & 15, g = l >> 4;
    bf16* Alb = (bf16*)Al;

    // stage A = O tile, B = Wo
    #pragma unroll
    for (int i = 0; i < 4; ++i) {
        const int lin = i * 256 + tid;
        const int r = lin >> 4, u = lin & 15;
        Al[r * 16 + (u ^ (r & 7))] =
            *(const bf16x8*)(Ob + (size_t)(m0 + r) * E_ + u * 8);
    }
    #pragma unroll
    for (int i = 0; i < 8; ++i) {
        const int lin = i * 256 + tid;
        const int r = lin >> 4, u = lin & 15;
        Bl[r * 16 + (u ^ (r & 7))] =
            *(const bf16x8*)(Wd + 49152 + (size_t)r * E_ + u * 8);
    }
    __syncthreads();

    const int mr = w * 16 + l15;
    f32x4 acc[8];

    // ---- step 1: O@Wo ----
    #pragma unroll
    for (int nf = 0; nf < 8; ++nf) acc[nf] = f32x4{0.f, 0.f, 0.f, 0.f};
    #pragma unroll
    for (int s = 0; s < 4; ++s) {
        const int ua = s * 4 + g;
        const bf16x8 a = Al[mr * 16 + (ua ^ (mr & 7))];
        #pragma unroll
        for (int nf = 0; nf < 8; ++nf) {
            const int nr = nf * 16 + l15;
            acc[nf] = __builtin_amdgcn_mfma_f32_16x16x32_bf16(
                a, Bl[nr * 16 + (ua ^ (nr & 7))], acc[nf], 0, 0, 0);
        }
    }
    // ep1: x1 = LN1(acc + bo + X); keep f32 in regs; write bf16 to Al
    float x1[8][4];
    #pragma unroll
    for (int fr = 0; fr < 4; ++fr) {
        const int rloc = w * 16 + g * 4 + fr;
        const int grow = m0 + rloc;
        float s1 = 0.f, s2 = 0.f;
        float v[8];
        #pragma unroll
        for (int nf = 0; nf < 8; ++nf) {
            const int col = nf * 16 + l15;
            const float xv = acc[nf][fr] + bo[col] + X[(size_t)grow * E_ + col];
            v[nf] = xv; s1 += xv; s2 += xv * xv;
        }
        #pragma unroll
        for (int off = 1; off < 16; off <<= 1) {
            s1 += __shfl_xor(s1, off);
            s2 += __shfl_xor(s2, off);
        }
        const float mu = s1 * (1.f / 128.f);
        const float rstd = rsqrtf(s2 * (1.f / 128.f) - mu * mu + LN_EPS);
        #pragma unroll
        for (int nf = 0; nf < 8; ++nf) {
            const int col = nf * 16 + l15;
            const float xo = (v[nf] - mu) * rstd * ln1g[col] + ln1b[col];
            x1[nf][fr] = xo;
            const int u = col >> 3;
            Alb[(rloc * 16 + (u ^ (rloc & 7))) * 8 + (col & 7)] = __float2bfloat16(xo);
        }
    }

    // ---- step 2: relu(x1@W1 + b1) ----
    __syncthreads();                       // all waves done reading Bl(Wo)
    #pragma unroll
    for (int i = 0; i < 8; ++i) {
        const int lin = i * 256 + tid;
        const int r = lin >> 4, u = lin & 15;
        Bl[r * 16 + (u ^ (r & 7))] =
            *(const bf16x8*)(Wd + 65536 + (size_t)r * E_ + u * 8);
    }
    __syncthreads();
    #pragma unroll
    for (int nf = 0; nf < 8; ++nf) acc[nf] = f32x4{0.f, 0.f, 0.f, 0.f};
    #pragma unroll
    for (int s = 0; s < 4; ++s) {
        const int ua = s * 4 + g;
        const bf16x8 a = Al[mr * 16 + (ua ^ (mr & 7))];
        #pragma unroll
        for (int nf = 0; nf < 8; ++nf) {
            const int nr = nf * 16 + l15;
            acc[nf] = __builtin_amdgcn_mfma_f32_16x16x32_bf16(
                a, Bl[nr * 16 + (ua ^ (nr & 7))], acc[nf], 0, 0, 0);
        }
    }
    #pragma unroll
    for (int fr = 0; fr < 4; ++fr) {
        const int rloc = w * 16 + g * 4 + fr;
        #pragma unroll
        for (int nf = 0; nf < 8; ++nf) {
            const int col = nf * 16 + l15;
            const float f = fmaxf(acc[nf][fr] + b1[col], 0.f);
            const int u = col >> 3;
            Alb[(rloc * 16 + (u ^ (rloc & 7))) * 8 + (col & 7)] = __float2bfloat16(f);
        }
    }

    // ---- step 3: LN2(x1 + f1@W2 + b2) -> X ; pool partials in registers ----
    __syncthreads();
    #pragma unroll
    for (int i = 0; i < 8; ++i) {
        const int lin = i * 256 + tid;
        const int r = lin >> 4, u = lin & 15;
        Bl[r * 16 + (u ^ (r & 7))] =
            *(const bf16x8*)(Wd + 81920 + (size_t)r * E_ + u * 8);
    }
    __syncthreads();
    #pragma unroll
    for (int nf = 0; nf < 8; ++nf) acc[nf] = f32x4{0.f, 0.f, 0.f, 0.f};
    #pragma unroll
    for (int s = 0; s < 4; ++s) {
        const int ua = s * 4 + g;
        const bf16x8 a = Al[mr * 16 + (ua ^ (mr & 7))];
        #pragma unroll
        for (int nf = 0; nf < 8; ++nf) {
            const int nr = nf * 16 + l15;
            acc[nf] = __builtin_amdgcn_mfma_f32_16x16x32_bf16(
                a, Bl[nr * 16 + (ua ^ (nr & 7))], acc[nf], 0, 0, 0);
        }
    }
    float pp0[8] = {0.f, 0.f, 0.f, 0.f, 0.f, 0.f, 0.f, 0.f};
    float pp1[8] = {0.f, 0.f, 0.f, 0.f, 0.f, 0.f, 0.f, 0.f};
    #pragma unroll
    for (int fr = 0; fr < 4; ++fr) {
        const int grow = m0 + w * 16 + g * 4 + fr;
        const int bb = grow / S_, ss = grow - bb * S_;
        const int bl = bb - b0;
        float s1 = 0.f, s2 = 0.f;
        float v[8];
        #pragma unroll
        for (int nf = 0; nf < 8; ++nf) {
            const int col = nf * 16 + l15;
            const float xv = acc[nf][fr] + b2[col] + x1[nf][fr];
            v[nf] = xv; s1 += xv; s2 += xv * xv;
        }
        #pragma unroll
        for (int off = 1; off < 16; off <<= 1) {
            s1 += __shfl_xor(s1, off);
            s2 += __shfl_xor(s2, off);
        }
        const float mu = s1 * (1.f / 128.f);
        const float rstd = rsqrtf(s2 * (1.f / 128.f) - mu * mu + LN_EPS);
        #pragma unroll
        for (int nf = 0; nf < 8; ++nf) {
            const int col = nf * 16 + l15;
            const float xo = (v[nf] - mu) * rstd * ln2g[col] + ln2b[col];
            X[(size_t)grow * E_ + col] = xo;
            if (ss > 0) {                       // static-indexed partials (rule #20)
                if (bl == 0) pp0[nf] += xo;
                else         pp1[nf] += xo;
            }
        }
    }
    // reduce across g-groups (lanes ^16, ^32 share l15 and wave)
    #pragma unroll
    for (int nf = 0; nf < 8; ++nf) {
        pp0[nf] += __shfl_xor(pp0[nf], 16); pp0[nf] += __shfl_xor(pp0[nf], 32);
        pp1[nf] += __shfl_xor(pp1[nf], 16); pp1[nf] += __shfl_xor(pp1[nf], 32);
    }
    if (l < 16) {
        #pragma unroll
        for (int nf = 0; nf < 8; ++nf) {
            hbw[w][0][nf * 16 + l15] = pp0[nf];
            hbw[w][1][nf * 16 + l15] = pp1[nf];
        }
    }
    __syncthreads();
    {
        const int bl = tid >> 7, col = tid & 127;
        const int bb = b0 + bl;
        const float v = hbw[0][bl][col] + hbw[1][bl][col] +
                        hbw[2][bl][col] + hbw[3][bl][col];
        if (bb < B_) atomicAdd(&hb[bb * 128 + col], v * (1.f / 128.f));
    }
}

// ---------------------------------------------------------------------------
// MFMA attention v2 (round-9 proven version, unchanged)
// ---------------------------------------------------------------------------
__global__ __launch_bounds__(256)
void attn_mfma(bf16* __restrict__ qb, const bf16* __restrict__ kb,
               const bf16* __restrict__ vb) {
    __shared__ __align__(16) bf16x8 Ks[144 * 8];      // 18 KiB, swizzled
    __shared__ __align__(16) bf16  Vt[64 * 168];      // 21 KiB, V^T
    __shared__ __align__(16) bf16  Pb[4][16 * 168];   // 21 KiB, per-wave P
    const int tid = threadIdx.x;
    const int w = tid >> 6, l = tid & 63;
    const int l15 = l & 15, g = l >> 4;
    const int blk = blockIdx.x;
    const int half = blk & 1;
    const int h = (blk >> 1) & (H_ - 1);
    const int b = blk >> 2;
    const size_t base = ((size_t)b * S_) * E_ + h * HD;

    for (int idx = tid; idx < 144 * 8; idx += 256) {
        const int r = idx >> 3, u = idx & 7;
        bf16x8 kv = {0, 0, 0, 0, 0, 0, 0, 0};
        if (r < S_) kv = *(const bf16x8*)(kb + base + (size_t)r * E_ + u * 8);
        Ks[r * 8 + (u ^ (r & 7))] = kv;
    }
    for (int idx = tid; idx < 168 * 64; idx += 256) {
        const int t = idx >> 6, d = idx & 63;
        Vt[d * 168 + t] = (t < S_) ? vb[base + (size_t)t * E_ + d]
                                   : __float2bfloat16(0.f);
    }
    __syncthreads();

    bf16* P = Pb[w];
    for (int rt = (half ? 5 : 0) + w; rt < (half ? 9 : 5); rt += 4) {
        const int qr0 = rt * 16 + l15;
        const int qrow = (qr0 < S_) ? qr0 : (S_ - 1);
        const bf16x8 aq0 = *(const bf16x8*)(qb + base + (size_t)qrow * E_ + g * 8);
        const bf16x8 aq1 = *(const bf16x8*)(qb + base + (size_t)qrow * E_ + 32 + g * 8);

        f32x4 acc[9];
        #pragma unroll
        for (int ct = 0; ct < 9; ++ct) {
            const int kr = ct * 16 + l15;
            f32x4 a = {0.f, 0.f, 0.f, 0.f};
            a = __builtin_amdgcn_mfma_f32_16x16x32_bf16(
                    aq0, Ks[kr * 8 + (g ^ (kr & 7))], a, 0, 0, 0);
            a = __builtin_amdgcn_mfma_f32_16x16x32_bf16(
                    aq1, Ks[kr * 8 + ((4 + g) ^ (kr & 7))], a, 0, 0, 0);
            acc[ct] = a;
        }

        const bool tail = (l15 != 0);
        float mx[4] = {-1e30f, -1e30f, -1e30f, -1e30f};
        #pragma unroll
        for (int ct = 0; ct < 9; ++ct)
            #pragma unroll
            for (int r = 0; r < 4; ++r) {
                const float v = acc[ct][r] * 0.125f;
                acc[ct][r] = v;
                if (ct < 8 || !tail) mx[r] = fmaxf(mx[r], v);
            }
        #pragma unroll
        for (int r = 0; r < 4; ++r)
            #pragma unroll
            for (int off = 1; off < 16; off <<= 1)
                mx[r] = fmaxf(mx[r], __shfl_xor(mx[r], off));
        float sm[4] = {0.f, 0.f, 0.f, 0.f};
        #pragma unroll
        for (int ct = 0; ct < 9; ++ct)
            #pragma unroll
            for (int r = 0; r < 4; ++r) {
                const float p = (ct < 8 || !tail) ? __expf(acc[ct][r] - mx[r]) : 0.f;
                acc[ct][r] = p;
                sm[r] += p;
            }
        #pragma unroll
        for (int r = 0; r < 4; ++r) {
            #pragma unroll
            for (int off = 1; off < 16; off <<= 1)
                sm[r] += __shfl_xor(sm[r], off);
            sm[r] = 1.f / sm[r];
        }

        #pragma unroll
        for (int ct = 0; ct < 9; ++ct)
            #pragma unroll
            for (int r = 0; r < 4; ++r)
                P[(g * 4 + r) * 168 + ct * 16 + l15] =
                    __float2bfloat16(acc[ct][r] * sm[r]);
        #pragma unroll
        for (int r = 0; r < 4; ++r)
            P[(g * 4 + r) * 168 + 144 + l15] = __float2bfloat16(0.f);

        #pragma unroll
        for (int co = 0; co < 4; ++co) {
            f32x4 o = {0.f, 0.f, 0.f, 0.f};
            #pragma unroll
            for (int kc = 0; kc < 5; ++kc) {
                const bf16x8 pa = *(const bf16x8*)(P + l15 * 168 + kc * 32 + g * 8);
                const bf16x8 vv = *(const bf16x8*)(Vt + (co * 16 + l15) * 168 + kc * 32 + g * 8);
                o = __builtin_amdgcn_mfma_f32_16x16x32_bf16(pa, vv, o, 0, 0, 0);
            }
            #pragma unroll
            for (int r = 0; r < 4; ++r) {
                const int orow = rt * 16 + g * 4 + r;
                if (orow < S_)
                    qb[base + (size_t)orow * E_ + co * 16 + l15] =
                        __float2bfloat16(o[r]);
            }
        }
    }
}

// ---------------------------------------------------------------------------
extern "C" void kernel_launch(void* const* d_in, const int* in_sizes, int n_in,
                              void* d_out, int out_size, void* d_ws, size_t ws_size,
                              hipStream_t stream) {
    const int* cat_arr      = (const int*)d_in[0];
    const int* dt_arr       = (const int*)d_in[1];
    const int* amount_arr   = (const int*)d_in[2];
    const int* id_arr       = (const int*)d_in[3];
    const float* id_table   = (const float*)d_in[4];
    const float* cat_table  = (const float*)d_in[5];
    const float* amount_tab = (const float*)d_in[6];
    const float* dt_table   = (const float*)d_in[7];
    const float* Wq = (const float*)d_in[8];  const float* bq = (const float*)d_in[9];
    const float* Wk = (const float*)d_in[10]; const float* bk = (const float*)d_in[11];
    const float* Wv = (const float*)d_in[12]; const float* bv = (const float*)d_in[13];
    const float* Wo = (const float*)d_in[14]; const float* bo = (const float*)d_in[15];
    const float* ln1_g = (const float*)d_in[16]; const float* ln1_b = (const float*)d_in[17];
    const float* W1 = (const float*)d_in[18]; const float* b1 = (const float*)d_in[19];
    const float* W2 = (const float*)d_in[20]; const float* b2 = (const float*)d_in[21];
    const float* ln2_g = (const float*)d_in[22]; const float* ln2_b = (const float*)d_in[23];
    const float* lin1_W = (const float*)d_in[24]; const float* lin1_b = (const float*)d_in[25];
    const float* lin2_W = (const float*)d_in[26]; const float* lin2_b = (const float*)d_in[27];
    float* out = (float*)d_out;
    float* ws = (float*)d_ws;

    // Workspace (floats), total ~22.9 MiB:
    //   X[ME] | C0 bf16[ME] | D0 bf16[ME] | E0 bf16[ME] | Wd | bias1024 | catb | amtb | hb
    const size_t ME = (size_t)M_ * E_;           // 2,113,536
    float* X  = ws;                               // f32 x -> x2 (in-place)
    bf16* C0  = (bf16*)(ws + ME);                 // Kb
    bf16* D0  = (bf16*)(ws + ME + ME / 2);        // Qb -> Ob -> a1b
    bf16* E0  = (bf16*)(ws + 2 * ME);             // Vb
    bf16* Wd  = (bf16*)(ws + 2 * ME + ME / 2);    // 1,277,952 bf16
    float* bias1024 = ws + 2 * ME + ME / 2 + 638976;
    bf16* catb = (bf16*)(bias1024 + 1024);        // [1001][128] bf16 (row 1000 = 0)
    bf16* amtb = catb + 128128;                   // [101][128] bf16 (row 100 = 0)
    float* hb  = (float*)(amtb + 12928);          // [128][128] f32
    bf16* a1b = D0 + 16384;                       // [128][1024]

    prep_kernel<<<dim3(16, 16, 12), 256, 0, stream>>>(
        Wq, Wk, Wv, Wo, W1, W2, lin1_W, lin2_W, lin1_b, lin2_b,
        cat_table, amount_tab, Wd, bias1024, catb, amtb, hb, out);

    embed_kernel<<<M_, 256, 0, stream>>>(cat_arr, dt_arr, amount_arr, id_arr,
                                         id_table, catb, amtb, dt_table, X);

    // Fused QKV from f32 X: sel 0->Q(D0), 1->K(C0), 2->V(E0)
    gemm_mfma<false,false,false,false,true,false,true,true,false>
        <<<dim3(M_ / 64, 3), 256, 0, stream>>>(
        X, Wd, bq, bk, bv, nullptr, nullptr, D0, C0, E0, nullptr, nullptr,
        128, 128, 128);

    attn_mfma<<<B_ * H_ * 2, 256, 0, stream>>>(D0, C0, E0);   // Ob -> D0

    // Fused tail + pool: X = LN2(...), hb += pooled means (hb zeroed by prep)
    encoder_tail<<<M_ / 64, 256, 0, stream>>>(
        D0, Wd, bo, b1, b2, ln1_g, ln1_b, ln2_g, ln2_b, X, hb);

    // a1b = relu(hb@lin1 + b) [128][1024] (A is f32 via AF32 staging)
    gemm_mfma<true,false,false,false,true,false,true,false,false>
        <<<dim3(2, 8), 256, 0, stream>>>(
        hb, Wd + 98304, bias1024, nullptr, nullptr, nullptr, nullptr, a1b,
        nullptr, nullptr, nullptr, nullptr, 128, 1024, 1024);
    // out += a1b@lin2 partials (K=1024 split 8 ways, atomic; out pre-set to bias)
    gemm_mfma<false,false,false,true,false,true,false,false,true>
        <<<dim3(2, 8, 8), 256, 0, stream>>>(
        a1b, Wd + 229376, nullptr, nullptr, nullptr, nullptr, out, nullptr,
        nullptr, nullptr, nullptr, nullptr, 1024, 1000, 1000);
}

// Round 13
// 129.704 us; speedup vs baseline: 1.0016x; 1.0016x over previous
//
#include <hip/hip_runtime.h>
#include <hip/hip_bf16.h>

#define B_ 128
#define L_ 128
#define J_ 64
#define E_ 128
#define H_ 2
#define HD 64
#define S_ 129          // L+1
#define M_ (B_ * S_)    // 16512 tokens
#define CAT_ 1000
#define LN_EPS 1e-5f

typedef __attribute__((ext_vector_type(8))) short bf16x8;
typedef __attribute__((ext_vector_type(4))) float f32x4;
typedef __hip_bfloat16 bf16;

__device__ inline float bf2f(unsigned short u) {
    union { unsigned int i; float f; } v; v.i = (unsigned int)u << 16; return v.f;
}
__device__ inline unsigned short f2bu(float f) {
    __hip_bfloat16 h = __float2bfloat16(f);
    return *reinterpret_cast<unsigned short*>(&h);
}

// ---------------------------------------------------------------------------
// prep: transpose+convert weights to bf16 Bt[N][K]; pad lin1/lin2; pad bias;
// z=8/9: tables->bf16 WITH trailing zero row (catb[1000]=0, amtb[100]=0);
// z=10: zero hb; z=11: out = lin2 bias (every call).
// Wd bf16 offsets: q=0 k=16384 v=32768 o=49152 w1=65536 w2=81920
//                  lin1=98304 ([1024][128]) lin2=229376 ([1024][1024])
// ---------------------------------------------------------------------------
__global__ __launch_bounds__(256)
void prep_kernel(const float* __restrict__ Wq, const float* __restrict__ Wk,
                 const float* __restrict__ Wv, const float* __restrict__ Wo,
                 const float* __restrict__ W1, const float* __restrict__ W2,
                 const float* __restrict__ lin1W, const float* __restrict__ lin2W,
                 const float* __restrict__ lin1b, const float* __restrict__ lin2b,
                 const float* __restrict__ cat_table, const float* __restrict__ amount_table,
                 bf16* __restrict__ Wd, float* __restrict__ bias1024,
                 bf16* __restrict__ catb, bf16* __restrict__ amtb,
                 float* __restrict__ hb, float* __restrict__ outp) {
    const int z = blockIdx.z;
    const int tid = threadIdx.x;
    if (z == 8) {   // cat_table -> bf16, 1001 rows (row 1000 = zeros)
        const int gid = (blockIdx.x * 16 + blockIdx.y) * 256 + tid;
        for (int i = gid; i < 1001 * 128; i += 65536)
            catb[i] = (i < 1000 * 128) ? __float2bfloat16(cat_table[i])
                                       : __float2bfloat16(0.f);
        return;
    }
    if (z == 9) {   // amount_table -> bf16, 101 rows (row 100 = zeros)
        const int gid = (blockIdx.x * 16 + blockIdx.y) * 256 + tid;
        for (int i = gid; i < 101 * 128; i += 65536)
            amtb[i] = (i < 100 * 128) ? __float2bfloat16(amount_table[i])
                                      : __float2bfloat16(0.f);
        return;
    }
    if (z == 10) {  // zero hb [128][128] f32 (tail atomics accumulate into it)
        const int gid = (blockIdx.x * 16 + blockIdx.y) * 256 + tid;
        if (gid < B_ * E_) hb[gid] = 0.f;
        return;
    }
    if (z == 11) {  // out[128][1000] = lin2 bias (lin2 atomically adds partials)
        const int gid = (blockIdx.x * 16 + blockIdx.y) * 256 + tid;
        for (int i = gid; i < B_ * CAT_; i += 65536)
            outp[i] = lin2b[i % CAT_];
        return;
    }
    const float* src; bf16* dst; int Kd, Nd, sK, sN;
    switch (z) {
        case 0: src = Wq;    dst = Wd;          Kd = 128;  Nd = 128;  sK = 128;  sN = 128;  break;
        case 1: src = Wk;    dst = Wd + 16384;  Kd = 128;  Nd = 128;  sK = 128;  sN = 128;  break;
        case 2: src = Wv;    dst = Wd + 32768;  Kd = 128;  Nd = 128;  sK = 128;  sN = 128;  break;
        case 3: src = Wo;    dst = Wd + 49152;  Kd = 128;  Nd = 128;  sK = 128;  sN = 128;  break;
        case 4: src = W1;    dst = Wd + 65536;  Kd = 128;  Nd = 128;  sK = 128;  sN = 128;  break;
        case 5: src = W2;    dst = Wd + 81920;  Kd = 128;  Nd = 128;  sK = 128;  sN = 128;  break;
        case 6: src = lin1W; dst = Wd + 98304;  Kd = 128;  Nd = 1024; sK = 128;  sN = 1000; break;
        default:src = lin2W; dst = Wd + 229376; Kd = 1024; Nd = 1024; sK = 1000; sN = 1000; break;
    }
    if (z == 7 && blockIdx.x == 0 && blockIdx.y == 0) {
        for (int i = tid; i < 1024; i += 256)
            bias1024[i] = (i < 1000) ? lin1b[i] : 0.f;
    }
    const int k0 = blockIdx.x * 64, n0 = blockIdx.y * 64;
    if (k0 >= Kd || n0 >= Nd) return;
    __shared__ float t[64][65];
    const int c = tid & 63, r0 = tid >> 6;
    #pragma unroll 4
    for (int i = 0; i < 16; ++i) {
        const int r = r0 + i * 4;
        const int gk = k0 + r, gn = n0 + c;
        t[r][c] = (gk < sK && gn < sN) ? src[(size_t)gk * sN + gn] : 0.f;
    }
    __syncthreads();
    #pragma unroll 4
    for (int i = 0; i < 16; ++i) {
        const int r = r0 + i * 4;
        dst[(size_t)(n0 + r) * Kd + (k0 + c)] = __float2bfloat16(t[c][r]);
    }
}

// ---------------------------------------------------------------------------
// Embedding v5: 16 tokens/block, 16 threads x 8 elems per token.
// amount_table staged in LDS (101 rows, stride 136 to rotate banks);
// cat rows gathered from L2; pad mask folded into zero-row indices.
// Each thread owns (token, 8 elems) fully -> no cross-thread reduce.
// ---------------------------------------------------------------------------
__global__ __launch_bounds__(256)
void embed_kernel(const int* __restrict__ cat_arr, const int* __restrict__ dt_arr,
                  const int* __restrict__ amount_arr, const int* __restrict__ id_arr,
                  const float* __restrict__ id_table, const bf16* __restrict__ catb,
                  const bf16* __restrict__ amtb, const float* __restrict__ dt_table,
                  float* __restrict__ x) {
    __shared__ __align__(16) bf16 amt_lds[101 * 136];  // 27.5 KiB (stride 136)
    __shared__ int coff[16][64];                       // 4 KiB (elem offs, catb)
    __shared__ int aoff[16][64];                       // 4 KiB (elem offs, amt_lds)
    const int tid = threadIdx.x;
    const int t0 = blockIdx.x * 16;

    // stage amount table: row r, unit u (8 bf16) -> amt_lds[r*136 + u*8]
    for (int i = tid; i < 101 * 16; i += 256) {
        const int r = i >> 4, u = i & 15;
        *(bf16x8*)(amt_lds + r * 136 + u * 8) =
            *(const bf16x8*)(amtb + r * 128 + u * 8);
    }
    // stage indices (pad -> zero rows; s==0 tokens get dummy zero rows)
    for (int idx = tid; idx < 16 * 64; idx += 256) {
        const int tok = idx >> 6, j = idx & 63;
        const int t = t0 + tok;
        const int b = t / S_, s = t - b * S_;
        if (s == 0) {
            coff[tok][j] = CAT_ * E_;
            aoff[tok][j] = 100 * 136;
        } else {
            const int base = (b * L_ + (s - 1)) * J_ + j;
            const int c = cat_arr[base];
            const int a = amount_arr[base];
            const bool valid = (c != CAT_);
            coff[tok][j] = (valid ? c : CAT_) * E_;
            aoff[tok][j] = (valid ? a : 100) * 136;
        }
    }
    __syncthreads();

    const int tok = tid >> 4;
    const int e8 = (tid & 15) * 8;
    const int t = t0 + tok;
    const int b = t / S_, s = t - b * S_;
    const size_t xoff = (size_t)t * E_ + e8;

    if (s == 0) {   // id token (no barrier after this point -> early exit safe)
        const size_t ib = (size_t)id_arr[b] * E_ + e8;
        *(float4*)(x + xoff)     = *(const float4*)(id_table + ib);
        *(float4*)(x + xoff + 4) = *(const float4*)(id_table + ib + 4);
        return;
    }

    float acc[8] = {0.f, 0.f, 0.f, 0.f, 0.f, 0.f, 0.f, 0.f};
    #pragma unroll 8
    for (int j = 0; j < 64; ++j) {
        const bf16x8 cu = *(const bf16x8*)(catb + coff[tok][j] + e8);
        const bf16x8 au = *(const bf16x8*)(amt_lds + aoff[tok][j] + e8);
        #pragma unroll
        for (int q = 0; q < 8; ++q)
            acc[q] += bf2f((unsigned short)cu[q]) + bf2f((unsigned short)au[q]);
    }
    const float* dtr = dt_table + (size_t)dt_arr[b * L_ + s - 1] * E_ + e8;
    float4 o0, o1;
    o0.x = acc[0] + dtr[0]; o0.y = acc[1] + dtr[1];
    o0.z = acc[2] + dtr[2]; o0.w = acc[3] + dtr[3];
    o1.x = acc[4] + dtr[4]; o1.y = acc[5] + dtr[5];
    o1.z = acc[6] + dtr[6]; o1.w = acc[7] + dtr[7];
    *(float4*)(x + xoff)     = o0;
    *(float4*)(x + xoff + 4) = o1;
}

// ---------------------------------------------------------------------------
// bf16 MFMA GEMM (QKV / lin1 / lin2 paths). ATOM: atomicAdd partials into Cf.
// ---------------------------------------------------------------------------
template<bool RELU, bool LN, bool HASRES, bool OF32, bool OBF16, bool SPLITK,
         bool AF32, bool QKV, bool ATOM>
__global__ __launch_bounds__(256)
void gemm_mfma(const void* __restrict__ Av, const bf16* __restrict__ Bt,
               const float* __restrict__ bias, const float* __restrict__ bias2,
               const float* __restrict__ bias3, const float* __restrict__ resid,
               float* __restrict__ Cf, bf16* __restrict__ Cb,
               bf16* __restrict__ Cb2, bf16* __restrict__ Cb3,
               const float* __restrict__ lng, const float* __restrict__ lnb,
               int K, int Nstride, int Nstore) {
    __shared__ bf16x8 Al[64 * 16];    // 16 KiB
    __shared__ bf16x8 Bl[128 * 16];   // 32 KiB
    const int tid = threadIdx.x;
    const int m0 = blockIdx.x * 64;
    const int n0 = QKV ? 0 : blockIdx.y * 128;
    const int w = tid >> 6, l = tid & 63;
    const int l15 = l & 15, g = l >> 4;
    f32x4 acc[8] = {};

    const bf16* BtX = Bt;
    const float* biasX = bias;
    bf16* CbX = Cb;
    if (QKV) {
        const int sel = blockIdx.y;
        BtX = Bt + sel * 16384;
        biasX = (sel == 0) ? bias : ((sel == 1) ? bias2 : bias3);
        CbX = (sel == 0) ? Cb : ((sel == 1) ? Cb2 : Cb3);
    }

    const int z = SPLITK ? blockIdx.z : 0;
    const int ksz = SPLITK ? (K / (int)gridDim.z) : K;
    const int kbeg = z * ksz;

    for (int kc = kbeg; kc < kbeg + ksz; kc += 128) {
        #pragma unroll
        for (int i = 0; i < 4; ++i) {
            const int lin = i * 256 + tid;
            const int r = lin >> 4, u = lin & 15;
            bf16x8 av;
            if (AF32) {
                const float* Af = (const float*)Av;
                const float4 f0 = *(const float4*)(Af + (size_t)(m0 + r) * K + kc + u * 8);
                const float4 f1 = *(const float4*)(Af + (size_t)(m0 + r) * K + kc + u * 8 + 4);
                av[0] = (short)f2bu(f0.x); av[1] = (short)f2bu(f0.y);
                av[2] = (short)f2bu(f0.z); av[3] = (short)f2bu(f0.w);
                av[4] = (short)f2bu(f1.x); av[5] = (short)f2bu(f1.y);
                av[6] = (short)f2bu(f1.z); av[7] = (short)f2bu(f1.w);
            } else {
                const bf16* Ab = (const bf16*)Av;
                av = *(const bf16x8*)(Ab + (size_t)(m0 + r) * K + kc + u * 8);
            }
            Al[r * 16 + (u ^ (r & 7))] = av;
        }
        #pragma unroll
        for (int i = 0; i < 8; ++i) {
            const int lin = i * 256 + tid;
            const int r = lin >> 4, u = lin & 15;
            Bl[r * 16 + (u ^ (r & 7))] =
                *(const bf16x8*)(BtX + (size_t)(n0 + r) * K + kc + u * 8);
        }
        __syncthreads();
        const int mr = w * 16 + l15;
        #pragma unroll
        for (int s = 0; s < 4; ++s) {
            const int ua = s * 4 + g;
            const bf16x8 a = Al[mr * 16 + (ua ^ (mr & 7))];
            #pragma unroll
            for (int nf = 0; nf < 8; ++nf) {
                const int nr = nf * 16 + l15;
                const bf16x8 b = Bl[nr * 16 + (ua ^ (nr & 7))];
                acc[nf] = __builtin_amdgcn_mfma_f32_16x16x32_bf16(a, b, acc[nf], 0, 0, 0);
            }
        }
        __syncthreads();
    }

    #pragma unroll
    for (int fr = 0; fr < 4; ++fr) {
        const int grow = m0 + w * 16 + g * 4 + fr;
        float v[8];
        float s1 = 0.f, s2 = 0.f;
        #pragma unroll
        for (int nf = 0; nf < 8; ++nf) {
            const int col = n0 + nf * 16 + l15;
            float xv = acc[nf][fr];
            if (!SPLITK && col < Nstore) xv += biasX[col];
            if (HASRES) xv += resid[(size_t)grow * Nstride + col];
            if (RELU) xv = fmaxf(xv, 0.f);
            v[nf] = xv;
            if (LN) { s1 += xv; s2 += xv * xv; }
        }
        if (LN) {
            #pragma unroll
            for (int off = 1; off < 16; off <<= 1) {
                s1 += __shfl_xor(s1, off);
                s2 += __shfl_xor(s2, off);
            }
            const float mu = s1 * (1.f / 128.f);
            const float rstd = rsqrtf(s2 * (1.f / 128.f) - mu * mu + LN_EPS);
            #pragma unroll
            for (int nf = 0; nf < 8; ++nf) {
                const int col = n0 + nf * 16 + l15;
                v[nf] = (v[nf] - mu) * rstd * lng[col] + lnb[col];
            }
        }
        float* Cfp = (SPLITK && !ATOM) ? (Cf + (size_t)z * (gridDim.x * 64) * Nstride) : Cf;
        #pragma unroll
        for (int nf = 0; nf < 8; ++nf) {
            const int col = n0 + nf * 16 + l15;
            if (col < Nstore) {
                if (OF32) {
                    if (ATOM) atomicAdd(&Cfp[(size_t)grow * Nstride + col], v[nf]);
                    else      Cfp[(size_t)grow * Nstride + col] = v[nf];
                }
                if (OBF16) CbX[(size_t)grow * Nstride + col] = __float2bfloat16(v[nf]);
            }
        }
    }
}

// ---------------------------------------------------------------------------
// Fused encoder tail + mean-pool (contention-free reduction).
//   X1 = LN1(X + O@Wo + bo); F1 = relu(X1@W1+b1); X = LN2(X1 + F1@W2 + b2);
//   pool: per-thread register partials -> shfl over g -> 4KB LDS over waves
//   -> 256 uncontended global atomicAdds into hb.
// ---------------------------------------------------------------------------
__global__ __launch_bounds__(256)
void encoder_tail(const bf16* __restrict__ Ob, const bf16* __restrict__ Wd,
                  const float* __restrict__ bo, const float* __restrict__ b1,
                  const float* __restrict__ b2,
                  const float* __restrict__ ln1g, const float* __restrict__ ln1b,
                  const float* __restrict__ ln2g, const float* __restrict__ ln2b,
                  float* __restrict__ X, float* __restrict__ hb) {
    __shared__ bf16x8 Al[64 * 16];    // 16 KiB
    __shared__ bf16x8 Bl[128 * 16];   // 32 KiB
    __shared__ float hbw[4][2][128];  // 4 KiB pool partials
    const int tid = threadIdx.x;
    const int m0 = blockIdx.x * 64;
    const int b0 = m0 / S_;
    const int w = tid >> 6, l = tid & 63;
    const int l15 = l & 15, g = l >> 4;
    bf16* Alb = (bf16*)Al;

    // stage A = O tile, B = Wo
    #pragma unroll
    for (int i = 0; i < 4; ++i) {
        const int lin = i * 256 + tid;
        const int r = lin >> 4, u = lin & 15;
        Al[r * 16 + (u ^ (r & 7))] =
            *(const bf16x8*)(Ob + (size_t)(m0 + r) * E_ + u * 8);
    }
    #pragma unroll
    for (int i = 0; i < 8; ++i) {
        const int lin = i * 256 + tid;
        const int r = lin >> 4, u = lin & 15;
        Bl[r * 16 + (u ^ (r & 7))] =
            *(const bf16x8*)(Wd + 49152 + (size_t)r * E_ + u * 8);
    }
    __syncthreads();

    const int mr = w * 16 + l15;
    f32x4 acc[8];

    // ---- step 1: O@Wo ----
    #pragma unroll
    for (int nf = 0; nf < 8; ++nf) acc[nf] = f32x4{0.f, 0.f, 0.f, 0.f};
    #pragma unroll
    for (int s = 0; s < 4; ++s) {
        const int ua = s * 4 + g;
        const bf16x8 a = Al[mr * 16 + (ua ^ (mr & 7))];
        #pragma unroll
        for (int nf = 0; nf < 8; ++nf) {
            const int nr = nf * 16 + l15;
            acc[nf] = __builtin_amdgcn_mfma_f32_16x16x32_bf16(
                a, Bl[nr * 16 + (ua ^ (nr & 7))], acc[nf], 0, 0, 0);
        }
    }
    // ep1: x1 = LN1(acc + bo + X); keep f32 in regs; write bf16 to Al
    float x1[8][4];
    #pragma unroll
    for (int fr = 0; fr < 4; ++fr) {
        const int rloc = w * 16 + g * 4 + fr;
        const int grow = m0 + rloc;
        float s1 = 0.f, s2 = 0.f;
        float v[8];
        #pragma unroll
        for (int nf = 0; nf < 8; ++nf) {
            const int col = nf * 16 + l15;
            const float xv = acc[nf][fr] + bo[col] + X[(size_t)grow * E_ + col];
            v[nf] = xv; s1 += xv; s2 += xv * xv;
        }
        #pragma unroll
        for (int off = 1; off < 16; off <<= 1) {
            s1 += __shfl_xor(s1, off);
            s2 += __shfl_xor(s2, off);
        }
        const float mu = s1 * (1.f / 128.f);
        const float rstd = rsqrtf(s2 * (1.f / 128.f) - mu * mu + LN_EPS);
        #pragma unroll
        for (int nf = 0; nf < 8; ++nf) {
            const int col = nf * 16 + l15;
            const float xo = (v[nf] - mu) * rstd * ln1g[col] + ln1b[col];
            x1[nf][fr] = xo;
            const int u = col >> 3;
            Alb[(rloc * 16 + (u ^ (rloc & 7))) * 8 + (col & 7)] = __float2bfloat16(xo);
        }
    }

    // ---- step 2: relu(x1@W1 + b1) ----
    __syncthreads();                       // all waves done reading Bl(Wo)
    #pragma unroll
    for (int i = 0; i < 8; ++i) {
        const int lin = i * 256 + tid;
        const int r = lin >> 4, u = lin & 15;
        Bl[r * 16 + (u ^ (r & 7))] =
            *(const bf16x8*)(Wd + 65536 + (size_t)r * E_ + u * 8);
    }
    __syncthreads();
    #pragma unroll
    for (int nf = 0; nf < 8; ++nf) acc[nf] = f32x4{0.f, 0.f, 0.f, 0.f};
    #pragma unroll
    for (int s = 0; s < 4; ++s) {
        const int ua = s * 4 + g;
        const bf16x8 a = Al[mr * 16 + (ua ^ (mr & 7))];
        #pragma unroll
        for (int nf = 0; nf < 8; ++nf) {
            const int nr = nf * 16 + l15;
            acc[nf] = __builtin_amdgcn_mfma_f32_16x16x32_bf16(
                a, Bl[nr * 16 + (ua ^ (nr & 7))], acc[nf], 0, 0, 0);
        }
    }
    #pragma unroll
    for (int fr = 0; fr < 4; ++fr) {
        const int rloc = w * 16 + g * 4 + fr;
        #pragma unroll
        for (int nf = 0; nf < 8; ++nf) {
            const int col = nf * 16 + l15;
            const float f = fmaxf(acc[nf][fr] + b1[col], 0.f);
            const int u = col >> 3;
            Alb[(rloc * 16 + (u ^ (rloc & 7))) * 8 + (col & 7)] = __float2bfloat16(f);
        }
    }

    // ---- step 3: LN2(x1 + f1@W2 + b2) -> X ; pool partials in registers ----
    __syncthreads();
    #pragma unroll
    for (int i = 0; i < 8; ++i) {
        const int lin = i * 256 + tid;
        const int r = lin >> 4, u = lin & 15;
        Bl[r * 16 + (u ^ (r & 7))] =
            *(const bf16x8*)(Wd + 81920 + (size_t)r * E_ + u * 8);
    }
    __syncthreads();
    #pragma unroll
    for (int nf = 0; nf < 8; ++nf) acc[nf] = f32x4{0.f, 0.f, 0.f, 0.f};
    #pragma unroll
    for (int s = 0; s < 4; ++s) {
        const int ua = s * 4 + g;
        const bf16x8 a = Al[mr * 16 + (ua ^ (mr & 7))];
        #pragma unroll
        for (int nf = 0; nf < 8; ++nf) {
            const int nr = nf * 16 + l15;
            acc[nf] = __builtin_amdgcn_mfma_f32_16x16x32_bf16(
                a, Bl[nr * 16 + (ua ^ (nr & 7))], acc[nf], 0, 0, 0);
        }
    }
    float pp0[8] = {0.f, 0.f, 0.f, 0.f, 0.f, 0.f, 0.f, 0.f};
    float pp1[8] = {0.f, 0.f, 0.f, 0.f, 0.f, 0.f, 0.f, 0.f};
    #pragma unroll
    for (int fr = 0; fr < 4; ++fr) {
        const int grow = m0 + w * 16 + g * 4 + fr;
        const int bb = grow / S_, ss = grow - bb * S_;
        const int bl = bb - b0;
        float s1 = 0.f, s2 = 0.f;
        float v[8];
        #pragma unroll
        for (int nf = 0; nf < 8; ++nf) {
            const int col = nf * 16 + l15;
            const float xv = acc[nf][fr] + b2[col] + x1[nf][fr];
            v[nf] = xv; s1 += xv; s2 += xv * xv;
        }
        #pragma unroll
        for (int off = 1; off < 16; off <<= 1) {
            s1 += __shfl_xor(s1, off);
            s2 += __shfl_xor(s2, off);
        }
        const float mu = s1 * (1.f / 128.f);
        const float rstd = rsqrtf(s2 * (1.f / 128.f) - mu * mu + LN_EPS);
        #pragma unroll
        for (int nf = 0; nf < 8; ++nf) {
            const int col = nf * 16 + l15;
            const float xo = (v[nf] - mu) * rstd * ln2g[col] + ln2b[col];
            X[(size_t)grow * E_ + col] = xo;
            if (ss > 0) {                       // static-indexed partials (rule #20)
                if (bl == 0) pp0[nf] += xo;
                else         pp1[nf] += xo;
            }
        }
    }
    // reduce across g-groups (lanes ^16, ^32 share l15 and wave)
    #pragma unroll
    for (int nf = 0; nf < 8; ++nf) {
        pp0[nf] += __shfl_xor(pp0[nf], 16); pp0[nf] += __shfl_xor(pp0[nf], 32);
        pp1[nf] += __shfl_xor(pp1[nf], 16); pp1[nf] += __shfl_xor(pp1[nf], 32);
    }
    if (l < 16) {
        #pragma unroll
        for (int nf = 0; nf < 8; ++nf) {
            hbw[w][0][nf * 16 + l15] = pp0[nf];
            hbw[w][1][nf * 16 + l15] = pp1[nf];
        }
    }
    __syncthreads();
    {
        const int bl = tid >> 7, col = tid & 127;
        const int bb = b0 + bl;
        const float v = hbw[0][bl][col] + hbw[1][bl][col] +
                        hbw[2][bl][col] + hbw[3][bl][col];
        if (bb < B_) atomicAdd(&hb[bb * 128 + col], v * (1.f / 128.f));
    }
}

// ---------------------------------------------------------------------------
// MFMA attention v2 (round-9 proven version, unchanged)
// ---------------------------------------------------------------------------
__global__ __launch_bounds__(256)
void attn_mfma(bf16* __restrict__ qb, const bf16* __restrict__ kb,
               const bf16* __restrict__ vb) {
    __shared__ __align__(16) bf16x8 Ks[144 * 8];      // 18 KiB, swizzled
    __shared__ __align__(16) bf16  Vt[64 * 168];      // 21 KiB, V^T
    __shared__ __align__(16) bf16  Pb[4][16 * 168];   // 21 KiB, per-wave P
    const int tid = threadIdx.x;
    const int w = tid >> 6, l = tid & 63;
    const int l15 = l & 15, g = l >> 4;
    const int blk = blockIdx.x;
    const int half = blk & 1;
    const int h = (blk >> 1) & (H_ - 1);
    const int b = blk >> 2;
    const size_t base = ((size_t)b * S_) * E_ + h * HD;

    for (int idx = tid; idx < 144 * 8; idx += 256) {
        const int r = idx >> 3, u = idx & 7;
        bf16x8 kv = {0, 0, 0, 0, 0, 0, 0, 0};
        if (r < S_) kv = *(const bf16x8*)(kb + base + (size_t)r * E_ + u * 8);
        Ks[r * 8 + (u ^ (r & 7))] = kv;
    }
    for (int idx = tid; idx < 168 * 64; idx += 256) {
        const int t = idx >> 6, d = idx & 63;
        Vt[d * 168 + t] = (t < S_) ? vb[base + (size_t)t * E_ + d]
                                   : __float2bfloat16(0.f);
    }
    __syncthreads();

    bf16* P = Pb[w];
    for (int rt = (half ? 5 : 0) + w; rt < (half ? 9 : 5); rt += 4) {
        const int qr0 = rt * 16 + l15;
        const int qrow = (qr0 < S_) ? qr0 : (S_ - 1);
        const bf16x8 aq0 = *(const bf16x8*)(qb + base + (size_t)qrow * E_ + g * 8);
        const bf16x8 aq1 = *(const bf16x8*)(qb + base + (size_t)qrow * E_ + 32 + g * 8);

        f32x4 acc[9];
        #pragma unroll
        for (int ct = 0; ct < 9; ++ct) {
            const int kr = ct * 16 + l15;
            f32x4 a = {0.f, 0.f, 0.f, 0.f};
            a = __builtin_amdgcn_mfma_f32_16x16x32_bf16(
                    aq0, Ks[kr * 8 + (g ^ (kr & 7))], a, 0, 0, 0);
            a = __builtin_amdgcn_mfma_f32_16x16x32_bf16(
                    aq1, Ks[kr * 8 + ((4 + g) ^ (kr & 7))], a, 0, 0, 0);
            acc[ct] = a;
        }

        const bool tail = (l15 != 0);
        float mx[4] = {-1e30f, -1e30f, -1e30f, -1e30f};
        #pragma unroll
        for (int ct = 0; ct < 9; ++ct)
            #pragma unroll
            for (int r = 0; r < 4; ++r) {
                const float v = acc[ct][r] * 0.125f;
                acc[ct][r] = v;
                if (ct < 8 || !tail) mx[r] = fmaxf(mx[r], v);
            }
        #pragma unroll
        for (int r = 0; r < 4; ++r)
            #pragma unroll
            for (int off = 1; off < 16; off <<= 1)
                mx[r] = fmaxf(mx[r], __shfl_xor(mx[r], off));
        float sm[4] = {0.f, 0.f, 0.f, 0.f};
        #pragma unroll
        for (int ct = 0; ct < 9; ++ct)
            #pragma unroll
            for (int r = 0; r < 4; ++r) {
                const float p = (ct < 8 || !tail) ? __expf(acc[ct][r] - mx[r]) : 0.f;
                acc[ct][r] = p;
                sm[r] += p;
            }
        #pragma unroll
        for (int r = 0; r < 4; ++r) {
            #pragma unroll
            for (int off = 1; off < 16; off <<= 1)
                sm[r] += __shfl_xor(sm[r], off);
            sm[r] = 1.f / sm[r];
        }

        #pragma unroll
        for (int ct = 0; ct < 9; ++ct)
            #pragma unroll
            for (int r = 0; r < 4; ++r)
                P[(g * 4 + r) * 168 + ct * 16 + l15] =
                    __float2bfloat16(acc[ct][r] * sm[r]);
        #pragma unroll
        for (int r = 0; r < 4; ++r)
            P[(g * 4 + r) * 168 + 144 + l15] = __float2bfloat16(0.f);

        #pragma unroll
        for (int co = 0; co < 4; ++co) {
            f32x4 o = {0.f, 0.f, 0.f, 0.f};
            #pragma unroll
            for (int kc = 0; kc < 5; ++kc) {
                const bf16x8 pa = *(const bf16x8*)(P + l15 * 168 + kc * 32 + g * 8);
                const bf16x8 vv = *(const bf16x8*)(Vt + (co * 16 + l15) * 168 + kc * 32 + g * 8);
                o = __builtin_amdgcn_mfma_f32_16x16x32_bf16(pa, vv, o, 0, 0, 0);
            }
            #pragma unroll
            for (int r = 0; r < 4; ++r) {
                const int orow = rt * 16 + g * 4 + r;
                if (orow < S_)
                    qb[base + (size_t)orow * E_ + co * 16 + l15] =
                        __float2bfloat16(o[r]);
            }
        }
    }
}

// ---------------------------------------------------------------------------
extern "C" void kernel_launch(void* const* d_in, const int* in_sizes, int n_in,
                              void* d_out, int out_size, void* d_ws, size_t ws_size,
                              hipStream_t stream) {
    const int* cat_arr      = (const int*)d_in[0];
    const int* dt_arr       = (const int*)d_in[1];
    const int* amount_arr   = (const int*)d_in[2];
    const int* id_arr       = (const int*)d_in[3];
    const float* id_table   = (const float*)d_in[4];
    const float* cat_table  = (const float*)d_in[5];
    const float* amount_tab = (const float*)d_in[6];
    const float* dt_table   = (const float*)d_in[7];
    const float* Wq = (const float*)d_in[8];  const float* bq = (const float*)d_in[9];
    const float* Wk = (const float*)d_in[10]; const float* bk = (const float*)d_in[11];
    const float* Wv = (const float*)d_in[12]; const float* bv = (const float*)d_in[13];
    const float* Wo = (const float*)d_in[14]; const float* bo = (const float*)d_in[15];
    const float* ln1_g = (const float*)d_in[16]; const float* ln1_b = (const float*)d_in[17];
    const float* W1 = (const float*)d_in[18]; const float* b1 = (const float*)d_in[19];
    const float* W2 = (const float*)d_in[20]; const float* b2 = (const float*)d_in[21];
    const float* ln2_g = (const float*)d_in[22]; const float* ln2_b = (const float*)d_in[23];
    const float* lin1_W = (const float*)d_in[24]; const float* lin1_b = (const float*)d_in[25];
    const float* lin2_W = (const float*)d_in[26]; const float* lin2_b = (const float*)d_in[27];
    float* out = (float*)d_out;
    float* ws = (float*)d_ws;

    // Workspace (floats), total ~22.9 MiB:
    //   X[ME] | C0 bf16[ME] | D0 bf16[ME] | E0 bf16[ME] | Wd | bias1024 | catb | amtb | hb
    const size_t ME = (size_t)M_ * E_;           // 2,113,536
    float* X  = ws;                               // f32 x -> x2 (in-place)
    bf16* C0  = (bf16*)(ws + ME);                 // Kb
    bf16* D0  = (bf16*)(ws + ME + ME / 2);        // Qb -> Ob -> a1b
    bf16* E0  = (bf16*)(ws + 2 * ME);             // Vb
    bf16* Wd  = (bf16*)(ws + 2 * ME + ME / 2);    // 1,277,952 bf16
    float* bias1024 = ws + 2 * ME + ME / 2 + 638976;
    bf16* catb = (bf16*)(bias1024 + 1024);        // [1001][128] bf16 (row 1000 = 0)
    bf16* amtb = catb + 128128;                   // [101][128] bf16 (row 100 = 0)
    float* hb  = (float*)(amtb + 12928);          // [128][128] f32
    bf16* a1b = D0 + 16384;                       // [128][1024]

    prep_kernel<<<dim3(16, 16, 12), 256, 0, stream>>>(
        Wq, Wk, Wv, Wo, W1, W2, lin1_W, lin2_W, lin1_b, lin2_b,
        cat_table, amount_tab, Wd, bias1024, catb, amtb, hb, out);

    embed_kernel<<<M_ / 16, 256, 0, stream>>>(cat_arr, dt_arr, amount_arr, id_arr,
                                              id_table, catb, amtb, dt_table, X);

    // Fused QKV from f32 X: sel 0->Q(D0), 1->K(C0), 2->V(E0)
    gemm_mfma<false,false,false,false,true,false,true,true,false>
        <<<dim3(M_ / 64, 3), 256, 0, stream>>>(
        X, Wd, bq, bk, bv, nullptr, nullptr, D0, C0, E0, nullptr, nullptr,
        128, 128, 128);

    attn_mfma<<<B_ * H_ * 2, 256, 0, stream>>>(D0, C0, E0);   // Ob -> D0

    // Fused tail + pool: X = LN2(...), hb += pooled means (hb zeroed by prep)
    encoder_tail<<<M_ / 64, 256, 0, stream>>>(
        D0, Wd, bo, b1, b2, ln1_g, ln1_b, ln2_g, ln2_b, X, hb);

    // a1b = relu(hb@lin1 + b) [128][1024] (A is f32 via AF32 staging)
    gemm_mfma<true,false,false,false,true,false,true,false,false>
        <<<dim3(2, 8), 256, 0, stream>>>(
        hb, Wd + 98304, bias1024, nullptr, nullptr, nullptr, nullptr, a1b,
        nullptr, nullptr, nullptr, nullptr, 128, 1024, 1024);
    // out += a1b@lin2 partials (K=1024 split 8 ways, atomic; out pre-set to bias)
    gemm_mfma<false,false,false,true,false,true,false,false,true>
        <<<dim3(2, 8, 8), 256, 0, stream>>>(
        a1b, Wd + 229376, nullptr, nullptr, nullptr, nullptr, out, nullptr,
        nullptr, nullptr, nullptr, nullptr, 1024, 1000, 1000);
}

// Round 14
// 112.055 us; speedup vs baseline: 1.1593x; 1.1575x over previous
//
#include <hip/hip_runtime.h>
#include <hip/hip_bf16.h>

#define B_ 128
#define L_ 128
#define J_ 64
#define E_ 128
#define H_ 2
#define HD 64
#define S_ 129          // L+1
#define M_ (B_ * S_)    // 16512 tokens
#define CAT_ 1000
#define LN_EPS 1e-5f

typedef __attribute__((ext_vector_type(8))) short bf16x8;
typedef __attribute__((ext_vector_type(4))) float f32x4;
typedef __hip_bfloat16 bf16;

__device__ inline float bf2f(unsigned short u) {
    union { unsigned int i; float f; } v; v.i = (unsigned int)u << 16; return v.f;
}
__device__ inline unsigned short f2bu(float f) {
    __hip_bfloat16 h = __float2bfloat16(f);
    return *reinterpret_cast<unsigned short*>(&h);
}

// ---------------------------------------------------------------------------
// prep: transpose+convert weights to bf16 Bt[N][K]; pad lin1/lin2; pad bias;
// z=8/9: tables->bf16 WITH trailing zero row; z=10: zero hb.
// Wd bf16 offsets: q=0 k=16384 v=32768 o=49152 w1=65536 w2=81920
//                  lin1=98304 ([1024][128]) lin2=229376 ([1024][1024])
// ---------------------------------------------------------------------------
__global__ __launch_bounds__(256)
void prep_kernel(const float* __restrict__ Wq, const float* __restrict__ Wk,
                 const float* __restrict__ Wv, const float* __restrict__ Wo,
                 const float* __restrict__ W1, const float* __restrict__ W2,
                 const float* __restrict__ lin1W, const float* __restrict__ lin2W,
                 const float* __restrict__ lin1b,
                 const float* __restrict__ cat_table, const float* __restrict__ amount_table,
                 bf16* __restrict__ Wd, float* __restrict__ bias1024,
                 bf16* __restrict__ catb, bf16* __restrict__ amtb,
                 float* __restrict__ hb) {
    const int z = blockIdx.z;
    const int tid = threadIdx.x;
    if (z == 8) {   // cat_table -> bf16, 1001 rows (row 1000 = zeros)
        const int gid = (blockIdx.x * 16 + blockIdx.y) * 256 + tid;
        for (int i = gid; i < 1001 * 128; i += 65536)
            catb[i] = (i < 1000 * 128) ? __float2bfloat16(cat_table[i])
                                       : __float2bfloat16(0.f);
        return;
    }
    if (z == 9) {   // amount_table -> bf16, 101 rows (row 100 = zeros)
        const int gid = (blockIdx.x * 16 + blockIdx.y) * 256 + tid;
        for (int i = gid; i < 101 * 128; i += 65536)
            amtb[i] = (i < 100 * 128) ? __float2bfloat16(amount_table[i])
                                      : __float2bfloat16(0.f);
        return;
    }
    if (z == 10) {  // zero hb [128][128] f32 (tail atomics accumulate into it)
        const int gid = (blockIdx.x * 16 + blockIdx.y) * 256 + tid;
        if (gid < B_ * E_) hb[gid] = 0.f;
        return;
    }
    const float* src; bf16* dst; int Kd, Nd, sK, sN;
    switch (z) {
        case 0: src = Wq;    dst = Wd;          Kd = 128;  Nd = 128;  sK = 128;  sN = 128;  break;
        case 1: src = Wk;    dst = Wd + 16384;  Kd = 128;  Nd = 128;  sK = 128;  sN = 128;  break;
        case 2: src = Wv;    dst = Wd + 32768;  Kd = 128;  Nd = 128;  sK = 128;  sN = 128;  break;
        case 3: src = Wo;    dst = Wd + 49152;  Kd = 128;  Nd = 128;  sK = 128;  sN = 128;  break;
        case 4: src = W1;    dst = Wd + 65536;  Kd = 128;  Nd = 128;  sK = 128;  sN = 128;  break;
        case 5: src = W2;    dst = Wd + 81920;  Kd = 128;  Nd = 128;  sK = 128;  sN = 128;  break;
        case 6: src = lin1W; dst = Wd + 98304;  Kd = 128;  Nd = 1024; sK = 128;  sN = 1000; break;
        default:src = lin2W; dst = Wd + 229376; Kd = 1024; Nd = 1024; sK = 1000; sN = 1000; break;
    }
    if (z == 7 && blockIdx.x == 0 && blockIdx.y == 0) {
        for (int i = tid; i < 1024; i += 256)
            bias1024[i] = (i < 1000) ? lin1b[i] : 0.f;
    }
    const int k0 = blockIdx.x * 64, n0 = blockIdx.y * 64;
    if (k0 >= Kd || n0 >= Nd) return;
    __shared__ float t[64][65];
    const int c = tid & 63, r0 = tid >> 6;
    #pragma unroll 4
    for (int i = 0; i < 16; ++i) {
        const int r = r0 + i * 4;
        const int gk = k0 + r, gn = n0 + c;
        t[r][c] = (gk < sK && gn < sN) ? src[(size_t)gk * sN + gn] : 0.f;
    }
    __syncthreads();
    #pragma unroll 4
    for (int i = 0; i < 16; ++i) {
        const int r = r0 + i * 4;
        dst[(size_t)(n0 + r) * Kd + (k0 + c)] = __float2bfloat16(t[c][r]);
    }
}

// ---------------------------------------------------------------------------
// Embedding v5 (round-13): 16 tokens/block, amt table in LDS, zero-row pads.
// ---------------------------------------------------------------------------
__global__ __launch_bounds__(256)
void embed_kernel(const int* __restrict__ cat_arr, const int* __restrict__ dt_arr,
                  const int* __restrict__ amount_arr, const int* __restrict__ id_arr,
                  const float* __restrict__ id_table, const bf16* __restrict__ catb,
                  const bf16* __restrict__ amtb, const float* __restrict__ dt_table,
                  float* __restrict__ x) {
    __shared__ __align__(16) bf16 amt_lds[101 * 136];  // 27.5 KiB (stride 136)
    __shared__ int coff[16][64];
    __shared__ int aoff[16][64];
    const int tid = threadIdx.x;
    const int t0 = blockIdx.x * 16;

    for (int i = tid; i < 101 * 16; i += 256) {
        const int r = i >> 4, u = i & 15;
        *(bf16x8*)(amt_lds + r * 136 + u * 8) =
            *(const bf16x8*)(amtb + r * 128 + u * 8);
    }
    for (int idx = tid; idx < 16 * 64; idx += 256) {
        const int tok = idx >> 6, j = idx & 63;
        const int t = t0 + tok;
        const int b = t / S_, s = t - b * S_;
        if (s == 0) {
            coff[tok][j] = CAT_ * E_;
            aoff[tok][j] = 100 * 136;
        } else {
            const int base = (b * L_ + (s - 1)) * J_ + j;
            const int c = cat_arr[base];
            const int a = amount_arr[base];
            const bool valid = (c != CAT_);
            coff[tok][j] = (valid ? c : CAT_) * E_;
            aoff[tok][j] = (valid ? a : 100) * 136;
        }
    }
    __syncthreads();

    const int tok = tid >> 4;
    const int e8 = (tid & 15) * 8;
    const int t = t0 + tok;
    const int b = t / S_, s = t - b * S_;
    const size_t xoff = (size_t)t * E_ + e8;

    if (s == 0) {
        const size_t ib = (size_t)id_arr[b] * E_ + e8;
        *(float4*)(x + xoff)     = *(const float4*)(id_table + ib);
        *(float4*)(x + xoff + 4) = *(const float4*)(id_table + ib + 4);
        return;
    }

    float acc[8] = {0.f, 0.f, 0.f, 0.f, 0.f, 0.f, 0.f, 0.f};
    #pragma unroll 8
    for (int j = 0; j < 64; ++j) {
        const bf16x8 cu = *(const bf16x8*)(catb + coff[tok][j] + e8);
        const bf16x8 au = *(const bf16x8*)(amt_lds + aoff[tok][j] + e8);
        #pragma unroll
        for (int q = 0; q < 8; ++q)
            acc[q] += bf2f((unsigned short)cu[q]) + bf2f((unsigned short)au[q]);
    }
    const float* dtr = dt_table + (size_t)dt_arr[b * L_ + s - 1] * E_ + e8;
    float4 o0, o1;
    o0.x = acc[0] + dtr[0]; o0.y = acc[1] + dtr[1];
    o0.z = acc[2] + dtr[2]; o0.w = acc[3] + dtr[3];
    o1.x = acc[4] + dtr[4]; o1.y = acc[5] + dtr[5];
    o1.z = acc[6] + dtr[6]; o1.w = acc[7] + dtr[7];
    *(float4*)(x + xoff)     = o0;
    *(float4*)(x + xoff + 4) = o1;
}

// ---------------------------------------------------------------------------
// bf16 MFMA GEMM — QKV path only now.
// ---------------------------------------------------------------------------
template<bool AF32, bool QKV>
__global__ __launch_bounds__(256)
void gemm_mfma(const void* __restrict__ Av, const bf16* __restrict__ Bt,
               const float* __restrict__ bias, const float* __restrict__ bias2,
               const float* __restrict__ bias3,
               bf16* __restrict__ Cb, bf16* __restrict__ Cb2, bf16* __restrict__ Cb3,
               int K) {
    __shared__ bf16x8 Al[64 * 16];    // 16 KiB
    __shared__ bf16x8 Bl[128 * 16];   // 32 KiB
    const int tid = threadIdx.x;
    const int m0 = blockIdx.x * 64;
    const int w = tid >> 6, l = tid & 63;
    const int l15 = l & 15, g = l >> 4;
    f32x4 acc[8] = {};

    const bf16* BtX = Bt;
    const float* biasX = bias;
    bf16* CbX = Cb;
    if (QKV) {
        const int sel = blockIdx.y;
        BtX = Bt + sel * 16384;
        biasX = (sel == 0) ? bias : ((sel == 1) ? bias2 : bias3);
        CbX = (sel == 0) ? Cb : ((sel == 1) ? Cb2 : Cb3);
    }

    for (int kc = 0; kc < K; kc += 128) {
        #pragma unroll
        for (int i = 0; i < 4; ++i) {
            const int lin = i * 256 + tid;
            const int r = lin >> 4, u = lin & 15;
            bf16x8 av;
            if (AF32) {
                const float* Af = (const float*)Av;
                const float4 f0 = *(const float4*)(Af + (size_t)(m0 + r) * K + kc + u * 8);
                const float4 f1 = *(const float4*)(Af + (size_t)(m0 + r) * K + kc + u * 8 + 4);
                av[0] = (short)f2bu(f0.x); av[1] = (short)f2bu(f0.y);
                av[2] = (short)f2bu(f0.z); av[3] = (short)f2bu(f0.w);
                av[4] = (short)f2bu(f1.x); av[5] = (short)f2bu(f1.y);
                av[6] = (short)f2bu(f1.z); av[7] = (short)f2bu(f1.w);
            } else {
                const bf16* Ab = (const bf16*)Av;
                av = *(const bf16x8*)(Ab + (size_t)(m0 + r) * K + kc + u * 8);
            }
            Al[r * 16 + (u ^ (r & 7))] = av;
        }
        #pragma unroll
        for (int i = 0; i < 8; ++i) {
            const int lin = i * 256 + tid;
            const int r = lin >> 4, u = lin & 15;
            Bl[r * 16 + (u ^ (r & 7))] =
                *(const bf16x8*)(BtX + (size_t)r * K + kc + u * 8);
        }
        __syncthreads();
        const int mr = w * 16 + l15;
        #pragma unroll
        for (int s = 0; s < 4; ++s) {
            const int ua = s * 4 + g;
            const bf16x8 a = Al[mr * 16 + (ua ^ (mr & 7))];
            #pragma unroll
            for (int nf = 0; nf < 8; ++nf) {
                const int nr = nf * 16 + l15;
                const bf16x8 b = Bl[nr * 16 + (ua ^ (nr & 7))];
                acc[nf] = __builtin_amdgcn_mfma_f32_16x16x32_bf16(a, b, acc[nf], 0, 0, 0);
            }
        }
        __syncthreads();
    }

    #pragma unroll
    for (int fr = 0; fr < 4; ++fr) {
        const int grow = m0 + w * 16 + g * 4 + fr;
        #pragma unroll
        for (int nf = 0; nf < 8; ++nf) {
            const int col = nf * 16 + l15;
            CbX[(size_t)grow * 128 + col] =
                __float2bfloat16(acc[nf][fr] + biasX[col]);
        }
    }
}

// ---------------------------------------------------------------------------
// Fused head: per block (x=rowhalf, y=out-col-slice, z=K-slice):
//   a1 = relu(hb[64r]@lin1[:, z*128..]) (K=128 MFMA) -> wave-local Al stripes
//   prt[z] = a1 @ lin2[z-K-slice, y-col-slice]       (K=128 MFMA, plain store)
// ---------------------------------------------------------------------------
__global__ __launch_bounds__(256)
void head_lin(const float* __restrict__ hb, const bf16* __restrict__ Wd,
              const float* __restrict__ bias1024, float* __restrict__ prt) {
    __shared__ bf16x8 Al[64 * 16];    // 16 KiB
    __shared__ bf16x8 Bl[128 * 16];   // 32 KiB
    const int tid = threadIdx.x;
    const int m0 = blockIdx.x * 64;
    const int y = blockIdx.y;
    const int z = blockIdx.z;
    const int w = tid >> 6, l = tid & 63;
    const int l15 = l & 15, g = l >> 4;
    bf16* Alb = (bf16*)Al;

    // stage A = hb tile (f32 -> bf16), B = lin1 rows z*128..z*128+127
    #pragma unroll
    for (int i = 0; i < 4; ++i) {
        const int lin = i * 256 + tid;
        const int r = lin >> 4, u = lin & 15;
        const float4 f0 = *(const float4*)(hb + (size_t)(m0 + r) * 128 + u * 8);
        const float4 f1 = *(const float4*)(hb + (size_t)(m0 + r) * 128 + u * 8 + 4);
        bf16x8 av;
        av[0] = (short)f2bu(f0.x); av[1] = (short)f2bu(f0.y);
        av[2] = (short)f2bu(f0.z); av[3] = (short)f2bu(f0.w);
        av[4] = (short)f2bu(f1.x); av[5] = (short)f2bu(f1.y);
        av[6] = (short)f2bu(f1.z); av[7] = (short)f2bu(f1.w);
        Al[r * 16 + (u ^ (r & 7))] = av;
    }
    #pragma unroll
    for (int i = 0; i < 8; ++i) {
        const int lin = i * 256 + tid;
        const int r = lin >> 4, u = lin & 15;
        Bl[r * 16 + (u ^ (r & 7))] =
            *(const bf16x8*)(Wd + 98304 + (size_t)(z * 128 + r) * 128 + u * 8);
    }
    __syncthreads();

    const int mr = w * 16 + l15;
    f32x4 acc[8];
    #pragma unroll
    for (int nf = 0; nf < 8; ++nf) acc[nf] = f32x4{0.f, 0.f, 0.f, 0.f};
    #pragma unroll
    for (int s = 0; s < 4; ++s) {
        const int ua = s * 4 + g;
        const bf16x8 a = Al[mr * 16 + (ua ^ (mr & 7))];
        #pragma unroll
        for (int nf = 0; nf < 8; ++nf) {
            const int nr = nf * 16 + l15;
            acc[nf] = __builtin_amdgcn_mfma_f32_16x16x32_bf16(
                a, Bl[nr * 16 + (ua ^ (nr & 7))], acc[nf], 0, 0, 0);
        }
    }
    // a1 = relu(acc + bias1024[z*128+col]) -> own Al stripe (wave-local)
    #pragma unroll
    for (int fr = 0; fr < 4; ++fr) {
        const int rloc = w * 16 + g * 4 + fr;
        #pragma unroll
        for (int nf = 0; nf < 8; ++nf) {
            const int col = nf * 16 + l15;
            const float f = fmaxf(acc[nf][fr] + bias1024[z * 128 + col], 0.f);
            const int u = col >> 3;
            Alb[(rloc * 16 + (u ^ (rloc & 7))) * 8 + (col & 7)] = __float2bfloat16(f);
        }
    }
    __syncthreads();
    // restage B = lin2 rows y*128.., K offset z*128
    #pragma unroll
    for (int i = 0; i < 8; ++i) {
        const int lin = i * 256 + tid;
        const int r = lin >> 4, u = lin & 15;
        Bl[r * 16 + (u ^ (r & 7))] =
            *(const bf16x8*)(Wd + 229376 + (size_t)(y * 128 + r) * 1024 + z * 128 + u * 8);
    }
    __syncthreads();
    #pragma unroll
    for (int nf = 0; nf < 8; ++nf) acc[nf] = f32x4{0.f, 0.f, 0.f, 0.f};
    #pragma unroll
    for (int s = 0; s < 4; ++s) {
        const int ua = s * 4 + g;
        const bf16x8 a = Al[mr * 16 + (ua ^ (mr & 7))];
        #pragma unroll
        for (int nf = 0; nf < 8; ++nf) {
            const int nr = nf * 16 + l15;
            acc[nf] = __builtin_amdgcn_mfma_f32_16x16x32_bf16(
                a, Bl[nr * 16 + (ua ^ (nr & 7))], acc[nf], 0, 0, 0);
        }
    }
    float* P = prt + (size_t)z * 131072;     // [128][1024]
    #pragma unroll
    for (int fr = 0; fr < 4; ++fr) {
        const int grow = m0 + w * 16 + g * 4 + fr;
        #pragma unroll
        for (int nf = 0; nf < 8; ++nf) {
            const int col = y * 128 + nf * 16 + l15;
            P[(size_t)grow * 1024 + col] = acc[nf][fr];
        }
    }
}

// reduce split-K partials [8][128][1024] -> out[128][1000] (+bias)
__global__ __launch_bounds__(256)
void splitk_reduce(const float* __restrict__ part, const float* __restrict__ bias,
                   float* __restrict__ out) {
    const int i = blockIdx.x * 256 + threadIdx.x;
    if (i >= B_ * CAT_) return;
    const int m = i / CAT_, n = i - m * CAT_;
    float v = bias[n];
    #pragma unroll
    for (int z = 0; z < 8; ++z) v += part[(size_t)z * 131072 + m * 1024 + n];
    out[i] = v;
}

// ---------------------------------------------------------------------------
// Fused encoder tail + mean-pool (round-13, unchanged)
// ---------------------------------------------------------------------------
__global__ __launch_bounds__(256)
void encoder_tail(const bf16* __restrict__ Ob, const bf16* __restrict__ Wd,
                  const float* __restrict__ bo, const float* __restrict__ b1,
                  const float* __restrict__ b2,
                  const float* __restrict__ ln1g, const float* __restrict__ ln1b,
                  const float* __restrict__ ln2g, const float* __restrict__ ln2b,
                  float* __restrict__ X, float* __restrict__ hb) {
    __shared__ bf16x8 Al[64 * 16];    // 16 KiB
    __shared__ bf16x8 Bl[128 * 16];   // 32 KiB
    __shared__ float hbw[4][2][128];  // 4 KiB pool partials
    const int tid = threadIdx.x;
    const int m0 = blockIdx.x * 64;
    const int b0 = m0 / S_;
    const int w = tid >> 6, l = tid & 63;
    const int l15 = l & 15, g = l >> 4;
    bf16* Alb = (bf16*)Al;

    #pragma unroll
    for (int i = 0; i < 4; ++i) {
        const int lin = i * 256 + tid;
        const int r = lin >> 4, u = lin & 15;
        Al[r * 16 + (u ^ (r & 7))] =
            *(const bf16x8*)(Ob + (size_t)(m0 + r) * E_ + u * 8);
    }
    #pragma unroll
    for (int i = 0; i < 8; ++i) {
        const int lin = i * 256 + tid;
        const int r = lin >> 4, u = lin & 15;
        Bl[r * 16 + (u ^ (r & 7))] =
            *(const bf16x8*)(Wd + 49152 + (size_t)r * E_ + u * 8);
    }
    __syncthreads();

    const int mr = w * 16 + l15;
    f32x4 acc[8];

    // ---- step 1: O@Wo ----
    #pragma unroll
    for (int nf = 0; nf < 8; ++nf) acc[nf] = f32x4{0.f, 0.f, 0.f, 0.f};
    #pragma unroll
    for (int s = 0; s < 4; ++s) {
        const int ua = s * 4 + g;
        const bf16x8 a = Al[mr * 16 + (ua ^ (mr & 7))];
        #pragma unroll
        for (int nf = 0; nf < 8; ++nf) {
            const int nr = nf * 16 + l15;
            acc[nf] = __builtin_amdgcn_mfma_f32_16x16x32_bf16(
                a, Bl[nr * 16 + (ua ^ (nr & 7))], acc[nf], 0, 0, 0);
        }
    }
    float x1[8][4];
    #pragma unroll
    for (int fr = 0; fr < 4; ++fr) {
        const int rloc = w * 16 + g * 4 + fr;
        const int grow = m0 + rloc;
        float s1 = 0.f, s2 = 0.f;
        float v[8];
        #pragma unroll
        for (int nf = 0; nf < 8; ++nf) {
            const int col = nf * 16 + l15;
            const float xv = acc[nf][fr] + bo[col] + X[(size_t)grow * E_ + col];
            v[nf] = xv; s1 += xv; s2 += xv * xv;
        }
        #pragma unroll
        for (int off = 1; off < 16; off <<= 1) {
            s1 += __shfl_xor(s1, off);
            s2 += __shfl_xor(s2, off);
        }
        const float mu = s1 * (1.f / 128.f);
        const float rstd = rsqrtf(s2 * (1.f / 128.f) - mu * mu + LN_EPS);
        #pragma unroll
        for (int nf = 0; nf < 8; ++nf) {
            const int col = nf * 16 + l15;
            const float xo = (v[nf] - mu) * rstd * ln1g[col] + ln1b[col];
            x1[nf][fr] = xo;
            const int u = col >> 3;
            Alb[(rloc * 16 + (u ^ (rloc & 7))) * 8 + (col & 7)] = __float2bfloat16(xo);
        }
    }

    // ---- step 2: relu(x1@W1 + b1) ----
    __syncthreads();
    #pragma unroll
    for (int i = 0; i < 8; ++i) {
        const int lin = i * 256 + tid;
        const int r = lin >> 4, u = lin & 15;
        Bl[r * 16 + (u ^ (r & 7))] =
            *(const bf16x8*)(Wd + 65536 + (size_t)r * E_ + u * 8);
    }
    __syncthreads();
    #pragma unroll
    for (int nf = 0; nf < 8; ++nf) acc[nf] = f32x4{0.f, 0.f, 0.f, 0.f};
    #pragma unroll
    for (int s = 0; s < 4; ++s) {
        const int ua = s * 4 + g;
        const bf16x8 a = Al[mr * 16 + (ua ^ (mr & 7))];
        #pragma unroll
        for (int nf = 0; nf < 8; ++nf) {
            const int nr = nf * 16 + l15;
            acc[nf] = __builtin_amdgcn_mfma_f32_16x16x32_bf16(
                a, Bl[nr * 16 + (ua ^ (nr & 7))], acc[nf], 0, 0, 0);
        }
    }
    #pragma unroll
    for (int fr = 0; fr < 4; ++fr) {
        const int rloc = w * 16 + g * 4 + fr;
        #pragma unroll
        for (int nf = 0; nf < 8; ++nf) {
            const int col = nf * 16 + l15;
            const float f = fmaxf(acc[nf][fr] + b1[col], 0.f);
            const int u = col >> 3;
            Alb[(rloc * 16 + (u ^ (rloc & 7))) * 8 + (col & 7)] = __float2bfloat16(f);
        }
    }

    // ---- step 3: LN2(x1 + f1@W2 + b2) -> X ; pool partials in registers ----
    __syncthreads();
    #pragma unroll
    for (int i = 0; i < 8; ++i) {
        const int lin = i * 256 + tid;
        const int r = lin >> 4, u = lin & 15;
        Bl[r * 16 + (u ^ (r & 7))] =
            *(const bf16x8*)(Wd + 81920 + (size_t)r * E_ + u * 8);
    }
    __syncthreads();
    #pragma unroll
    for (int nf = 0; nf < 8; ++nf) acc[nf] = f32x4{0.f, 0.f, 0.f, 0.f};
    #pragma unroll
    for (int s = 0; s < 4; ++s) {
        const int ua = s * 4 + g;
        const bf16x8 a = Al[mr * 16 + (ua ^ (mr & 7))];
        #pragma unroll
        for (int nf = 0; nf < 8; ++nf) {
            const int nr = nf * 16 + l15;
            acc[nf] = __builtin_amdgcn_mfma_f32_16x16x32_bf16(
                a, Bl[nr * 16 + (ua ^ (nr & 7))], acc[nf], 0, 0, 0);
        }
    }
    float pp0[8] = {0.f, 0.f, 0.f, 0.f, 0.f, 0.f, 0.f, 0.f};
    float pp1[8] = {0.f, 0.f, 0.f, 0.f, 0.f, 0.f, 0.f, 0.f};
    #pragma unroll
    for (int fr = 0; fr < 4; ++fr) {
        const int grow = m0 + w * 16 + g * 4 + fr;
        const int bb = grow / S_, ss = grow - bb * S_;
        const int bl = bb - b0;
        float s1 = 0.f, s2 = 0.f;
        float v[8];
        #pragma unroll
        for (int nf = 0; nf < 8; ++nf) {
            const int col = nf * 16 + l15;
            const float xv = acc[nf][fr] + b2[col] + x1[nf][fr];
            v[nf] = xv; s1 += xv; s2 += xv * xv;
        }
        #pragma unroll
        for (int off = 1; off < 16; off <<= 1) {
            s1 += __shfl_xor(s1, off);
            s2 += __shfl_xor(s2, off);
        }
        const float mu = s1 * (1.f / 128.f);
        const float rstd = rsqrtf(s2 * (1.f / 128.f) - mu * mu + LN_EPS);
        #pragma unroll
        for (int nf = 0; nf < 8; ++nf) {
            const int col = nf * 16 + l15;
            const float xo = (v[nf] - mu) * rstd * ln2g[col] + ln2b[col];
            X[(size_t)grow * E_ + col] = xo;
            if (ss > 0) {
                if (bl == 0) pp0[nf] += xo;
                else         pp1[nf] += xo;
            }
        }
    }
    #pragma unroll
    for (int nf = 0; nf < 8; ++nf) {
        pp0[nf] += __shfl_xor(pp0[nf], 16); pp0[nf] += __shfl_xor(pp0[nf], 32);
        pp1[nf] += __shfl_xor(pp1[nf], 16); pp1[nf] += __shfl_xor(pp1[nf], 32);
    }
    if (l < 16) {
        #pragma unroll
        for (int nf = 0; nf < 8; ++nf) {
            hbw[w][0][nf * 16 + l15] = pp0[nf];
            hbw[w][1][nf * 16 + l15] = pp1[nf];
        }
    }
    __syncthreads();
    {
        const int bl = tid >> 7, col = tid & 127;
        const int bb = b0 + bl;
        const float v = hbw[0][bl][col] + hbw[1][bl][col] +
                        hbw[2][bl][col] + hbw[3][bl][col];
        if (bb < B_) atomicAdd(&hb[bb * 128 + col], v * (1.f / 128.f));
    }
}

// ---------------------------------------------------------------------------
// MFMA attention v2 (round-9 proven version, unchanged)
// ---------------------------------------------------------------------------
__global__ __launch_bounds__(256)
void attn_mfma(bf16* __restrict__ qb, const bf16* __restrict__ kb,
               const bf16* __restrict__ vb) {
    __shared__ __align__(16) bf16x8 Ks[144 * 8];      // 18 KiB, swizzled
    __shared__ __align__(16) bf16  Vt[64 * 168];      // 21 KiB, V^T
    __shared__ __align__(16) bf16  Pb[4][16 * 168];   // 21 KiB, per-wave P
    const int tid = threadIdx.x;
    const int w = tid >> 6, l = tid & 63;
    const int l15 = l & 15, g = l >> 4;
    const int blk = blockIdx.x;
    const int half = blk & 1;
    const int h = (blk >> 1) & (H_ - 1);
    const int b = blk >> 2;
    const size_t base = ((size_t)b * S_) * E_ + h * HD;

    for (int idx = tid; idx < 144 * 8; idx += 256) {
        const int r = idx >> 3, u = idx & 7;
        bf16x8 kv = {0, 0, 0, 0, 0, 0, 0, 0};
        if (r < S_) kv = *(const bf16x8*)(kb + base + (size_t)r * E_ + u * 8);
        Ks[r * 8 + (u ^ (r & 7))] = kv;
    }
    for (int idx = tid; idx < 168 * 64; idx += 256) {
        const int t = idx >> 6, d = idx & 63;
        Vt[d * 168 + t] = (t < S_) ? vb[base + (size_t)t * E_ + d]
                                   : __float2bfloat16(0.f);
    }
    __syncthreads();

    bf16* P = Pb[w];
    for (int rt = (half ? 5 : 0) + w; rt < (half ? 9 : 5); rt += 4) {
        const int qr0 = rt * 16 + l15;
        const int qrow = (qr0 < S_) ? qr0 : (S_ - 1);
        const bf16x8 aq0 = *(const bf16x8*)(qb + base + (size_t)qrow * E_ + g * 8);
        const bf16x8 aq1 = *(const bf16x8*)(qb + base + (size_t)qrow * E_ + 32 + g * 8);

        f32x4 acc[9];
        #pragma unroll
        for (int ct = 0; ct < 9; ++ct) {
            const int kr = ct * 16 + l15;
            f32x4 a = {0.f, 0.f, 0.f, 0.f};
            a = __builtin_amdgcn_mfma_f32_16x16x32_bf16(
                    aq0, Ks[kr * 8 + (g ^ (kr & 7))], a, 0, 0, 0);
            a = __builtin_amdgcn_mfma_f32_16x16x32_bf16(
                    aq1, Ks[kr * 8 + ((4 + g) ^ (kr & 7))], a, 0, 0, 0);
            acc[ct] = a;
        }

        const bool tail = (l15 != 0);
        float mx[4] = {-1e30f, -1e30f, -1e30f, -1e30f};
        #pragma unroll
        for (int ct = 0; ct < 9; ++ct)
            #pragma unroll
            for (int r = 0; r < 4; ++r) {
                const float v = acc[ct][r] * 0.125f;
                acc[ct][r] = v;
                if (ct < 8 || !tail) mx[r] = fmaxf(mx[r], v);
            }
        #pragma unroll
        for (int r = 0; r < 4; ++r)
            #pragma unroll
            for (int off = 1; off < 16; off <<= 1)
                mx[r] = fmaxf(mx[r], __shfl_xor(mx[r], off));
        float sm[4] = {0.f, 0.f, 0.f, 0.f};
        #pragma unroll
        for (int ct = 0; ct < 9; ++ct)
            #pragma unroll
            for (int r = 0; r < 4; ++r) {
                const float p = (ct < 8 || !tail) ? __expf(acc[ct][r] - mx[r]) : 0.f;
                acc[ct][r] = p;
                sm[r] += p;
            }
        #pragma unroll
        for (int r = 0; r < 4; ++r) {
            #pragma unroll
            for (int off = 1; off < 16; off <<= 1)
                sm[r] += __shfl_xor(sm[r], off);
            sm[r] = 1.f / sm[r];
        }

        #pragma unroll
        for (int ct = 0; ct < 9; ++ct)
            #pragma unroll
            for (int r = 0; r < 4; ++r)
                P[(g * 4 + r) * 168 + ct * 16 + l15] =
                    __float2bfloat16(acc[ct][r] * sm[r]);
        #pragma unroll
        for (int r = 0; r < 4; ++r)
            P[(g * 4 + r) * 168 + 144 + l15] = __float2bfloat16(0.f);

        #pragma unroll
        for (int co = 0; co < 4; ++co) {
            f32x4 o = {0.f, 0.f, 0.f, 0.f};
            #pragma unroll
            for (int kc = 0; kc < 5; ++kc) {
                const bf16x8 pa = *(const bf16x8*)(P + l15 * 168 + kc * 32 + g * 8);
                const bf16x8 vv = *(const bf16x8*)(Vt + (co * 16 + l15) * 168 + kc * 32 + g * 8);
                o = __builtin_amdgcn_mfma_f32_16x16x32_bf16(pa, vv, o, 0, 0, 0);
            }
            #pragma unroll
            for (int r = 0; r < 4; ++r) {
                const int orow = rt * 16 + g * 4 + r;
                if (orow < S_)
                    qb[base + (size_t)orow * E_ + co * 16 + l15] =
                        __float2bfloat16(o[r]);
            }
        }
    }
}

// ---------------------------------------------------------------------------
extern "C" void kernel_launch(void* const* d_in, const int* in_sizes, int n_in,
                              void* d_out, int out_size, void* d_ws, size_t ws_size,
                              hipStream_t stream) {
    const int* cat_arr      = (const int*)d_in[0];
    const int* dt_arr       = (const int*)d_in[1];
    const int* amount_arr   = (const int*)d_in[2];
    const int* id_arr       = (const int*)d_in[3];
    const float* id_table   = (const float*)d_in[4];
    const float* cat_table  = (const float*)d_in[5];
    const float* amount_tab = (const float*)d_in[6];
    const float* dt_table   = (const float*)d_in[7];
    const float* Wq = (const float*)d_in[8];  const float* bq = (const float*)d_in[9];
    const float* Wk = (const float*)d_in[10]; const float* bk = (const float*)d_in[11];
    const float* Wv = (const float*)d_in[12]; const float* bv = (const float*)d_in[13];
    const float* Wo = (const float*)d_in[14]; const float* bo = (const float*)d_in[15];
    const float* ln1_g = (const float*)d_in[16]; const float* ln1_b = (const float*)d_in[17];
    const float* W1 = (const float*)d_in[18]; const float* b1 = (const float*)d_in[19];
    const float* W2 = (const float*)d_in[20]; const float* b2 = (const float*)d_in[21];
    const float* ln2_g = (const float*)d_in[22]; const float* ln2_b = (const float*)d_in[23];
    const float* lin1_W = (const float*)d_in[24]; const float* lin1_b = (const float*)d_in[25];
    const float* lin2_W = (const float*)d_in[26]; const float* lin2_b = (const float*)d_in[27];
    float* out = (float*)d_out;
    float* ws = (float*)d_ws;

    // Workspace (floats), total ~22.9 MiB:
    //   X[ME] | C0 bf16[ME] | D0 bf16[ME] | E0 bf16[ME] | Wd | bias1024 | catb | amtb | hb
    const size_t ME = (size_t)M_ * E_;           // 2,113,536
    float* X  = ws;                               // f32 x -> x2 (in-place)
    bf16* C0  = (bf16*)(ws + ME);                 // Kb
    bf16* D0  = (bf16*)(ws + ME + ME / 2);        // Qb -> Ob
    bf16* E0  = (bf16*)(ws + 2 * ME);             // Vb -> (f32 prt)
    bf16* Wd  = (bf16*)(ws + 2 * ME + ME / 2);    // 1,277,952 bf16
    float* bias1024 = ws + 2 * ME + ME / 2 + 638976;
    bf16* catb = (bf16*)(bias1024 + 1024);        // [1001][128] bf16 (row 1000 = 0)
    bf16* amtb = catb + 128128;                   // [101][128] bf16 (row 100 = 0)
    float* hb  = (float*)(amtb + 12928);          // [128][128] f32
    float* prt = (float*)E0;                      // [8][128][1024] f32 (4 MiB)

    prep_kernel<<<dim3(16, 16, 11), 256, 0, stream>>>(
        Wq, Wk, Wv, Wo, W1, W2, lin1_W, lin2_W, lin1_b,
        cat_table, amount_tab, Wd, bias1024, catb, amtb, hb);

    embed_kernel<<<M_ / 16, 256, 0, stream>>>(cat_arr, dt_arr, amount_arr, id_arr,
                                              id_table, catb, amtb, dt_table, X);

    // Fused QKV from f32 X: sel 0->Q(D0), 1->K(C0), 2->V(E0)
    gemm_mfma<true, true><<<dim3(M_ / 64, 3), 256, 0, stream>>>(
        X, Wd, bq, bk, bv, D0, C0, E0, 128);

    attn_mfma<<<B_ * H_ * 2, 256, 0, stream>>>(D0, C0, E0);   // Ob -> D0

    // Fused tail + pool: X = LN2(...), hb += pooled means (hb zeroed by prep)
    encoder_tail<<<M_ / 64, 256, 0, stream>>>(
        D0, Wd, bo, b1, b2, ln1_g, ln1_b, ln2_g, ln2_b, X, hb);

    // Fused head: a1 slice in-kernel, lin2 partials -> prt (no atomics)
    head_lin<<<dim3(2, 8, 8), 256, 0, stream>>>(hb, Wd, bias1024, prt);
    splitk_reduce<<<(B_ * CAT_ + 255) / 256, 256, 0, stream>>>(prt, lin2_b, out);
}